// Round 1
// baseline (8022.938 us; speedup 1.0000x reference)
//
#include <hip/hip_runtime.h>
#include <hip/hip_bf16.h>
#include <math.h>

#define SEQ 2048
#define HID 3584
#define NH 28
#define NKV 4
#define HD 128
#define GQA (NH / NKV)

// ---------------- fp32 tiled GEMM with optional bias ----------------
// C[M,N] = A[M,K] @ B[K,N] (+ bias[N]).  M,N multiples of 64, K multiple of 16.
__global__ __launch_bounds__(256) void gemm_bias_f32(
    const float* __restrict__ A, const float* __restrict__ B,
    const float* __restrict__ bias, float* __restrict__ C,
    int M, int N, int K) {
  __shared__ float As[16][65];  // As[k][m]
  __shared__ float Bs[16][65];  // Bs[k][n]
  const int tid = threadIdx.x;
  const int tx = tid & 15;      // n-dir
  const int ty = tid >> 4;      // m-dir
  const int bm = blockIdx.y * 64;
  const int bn = blockIdx.x * 64;
  float acc[4][4] = {};
  for (int k0 = 0; k0 < K; k0 += 16) {
#pragma unroll
    for (int i = 0; i < 4; i++) {
      int idx = tid + i * 256;          // 0..1023
      int ar = idx >> 4, ac = idx & 15; // A: 64 rows x 16 k
      As[ac][ar] = A[(size_t)(bm + ar) * K + k0 + ac];
      int bk = idx >> 6, bnn = idx & 63; // B: 16 k x 64 n
      Bs[bk][bnn] = B[(size_t)(k0 + bk) * N + bn + bnn];
    }
    __syncthreads();
#pragma unroll
    for (int kk = 0; kk < 16; kk++) {
      float a[4], b[4];
#pragma unroll
      for (int i = 0; i < 4; i++) a[i] = As[kk][ty * 4 + i];
#pragma unroll
      for (int j = 0; j < 4; j++) b[j] = Bs[kk][tx * 4 + j];
#pragma unroll
      for (int i = 0; i < 4; i++)
#pragma unroll
        for (int j = 0; j < 4; j++) acc[i][j] += a[i] * b[j];
    }
    __syncthreads();
  }
#pragma unroll
  for (int i = 0; i < 4; i++) {
    int r = bm + ty * 4 + i;
#pragma unroll
    for (int j = 0; j < 4; j++) {
      int cn = bn + tx * 4 + j;
      float v = acc[i][j];
      if (bias) v += bias[cn];
      C[(size_t)r * N + cn] = v;
    }
  }
}

// ---------------- RoPE (in-place) ----------------
// buf: [SEQ, nheads, 128]; cos/sin: [SEQ, 64]
__global__ void rope_kernel(float* __restrict__ buf,
                            const float* __restrict__ cosd,
                            const float* __restrict__ sind, int nheads) {
  const int s = blockIdx.x;
  const int h = blockIdx.y;
  const int d = threadIdx.x;  // 0..63
  const float c = cosd[s * 64 + d];
  const float sn = sind[s * 64 + d];
  float* p = buf + ((size_t)s * nheads + h) * HD;
  float x1 = p[d], x2 = p[d + 64];
  p[d] = x1 * c - x2 * sn;
  p[d + 64] = x1 * sn + x2 * c;
}

// ---------------- causal GQA flash attention ----------------
// q: [SEQ, NH, 128], k/v: [SEQ, NKV, 128], out: [SEQ, NH*128]
__global__ __launch_bounds__(256) void attn_kernel(
    const float* __restrict__ q, const float* __restrict__ k,
    const float* __restrict__ v, float* __restrict__ out) {
  const int qt = blockIdx.x;       // 32 q-tiles of 64 rows
  const int h = blockIdx.y;        // 28 heads
  const int kvh = h / GQA;
  const int row0 = qt * 64;
  const float scale = 0.08838834764831845f;  // 1/sqrt(128)

  __shared__ float qs[64][129];
  __shared__ float ks[32][129];
  __shared__ float vs[32][129];
  __shared__ float ss[64][33];

  const int tid = threadIdx.x;
  const int sub = tid & 3;    // 4 threads per q-row
  const int row = tid >> 2;   // 0..63

  // load Q tile
#pragma unroll
  for (int i = 0; i < 32; i++) {
    int idx = tid + i * 256;
    int r = idx >> 7, d = idx & 127;
    qs[r][d] = q[((size_t)(row0 + r) * NH + h) * HD + d];
  }

  float m = -INFINITY, l = 0.f;
  float o[32] = {};
  __syncthreads();

  const int nk = row0 + 64;  // keys 0 .. row0+63
  for (int kb = 0; kb < nk; kb += 32) {
    // load K,V tiles (32 x 128 each)
#pragma unroll
    for (int i = 0; i < 16; i++) {
      int idx = tid + i * 256;
      int r = idx >> 7, d = idx & 127;
      ks[r][d] = k[((size_t)(kb + r) * NKV + kvh) * HD + d];
      vs[r][d] = v[((size_t)(kb + r) * NKV + kvh) * HD + d];
    }
    __syncthreads();

    // scores for this thread: keys j = sub + 4*jj
    float sc[8];
    const int qr = row0 + row;
#pragma unroll
    for (int jj = 0; jj < 8; jj++) {
      int j = sub + 4 * jj;
      float acc = 0.f;
#pragma unroll 8
      for (int d = 0; d < 128; d++) acc += qs[row][d] * ks[j][d];
      sc[jj] = (kb + j <= qr) ? acc * scale : -INFINITY;
    }

    // online softmax update (4 threads per row cooperate; lanes are adjacent)
    float tmax = sc[0];
#pragma unroll
    for (int jj = 1; jj < 8; jj++) tmax = fmaxf(tmax, sc[jj]);
    tmax = fmaxf(tmax, __shfl_xor(tmax, 1));
    tmax = fmaxf(tmax, __shfl_xor(tmax, 2));
    float newm = fmaxf(m, tmax);     // finite after first tile (key 0 unmasked)
    float rescale = __expf(m - newm);  // m=-inf,newm finite -> 0
    float lsum = 0.f;
#pragma unroll
    for (int jj = 0; jj < 8; jj++) {
      float p = __expf(sc[jj] - newm);
      ss[row][sub + 4 * jj] = p;
      lsum += p;
    }
    lsum += __shfl_xor(lsum, 1);
    lsum += __shfl_xor(lsum, 2);
    l = l * rescale + lsum;
    m = newm;
#pragma unroll
    for (int d = 0; d < 32; d++) o[d] *= rescale;
    __syncthreads();

    // o[d] += sum_j p_j * v[j][d] over owned dims d in [sub*32, sub*32+32)
#pragma unroll 4
    for (int j = 0; j < 32; j++) {
      float pj = ss[row][j];
#pragma unroll
      for (int d = 0; d < 32; d++) o[d] += pj * vs[j][sub * 32 + d];
    }
    __syncthreads();
  }

  const float inv_l = 1.f / l;
#pragma unroll
  for (int d = 0; d < 32; d++) {
    out[(size_t)(row0 + row) * (NH * HD) + h * HD + sub * 32 + d] = o[d] * inv_l;
  }
}

extern "C" void kernel_launch(void* const* d_in, const int* in_sizes, int n_in,
                              void* d_out, int out_size, void* d_ws, size_t ws_size,
                              hipStream_t stream) {
  const float* x    = (const float*)d_in[0];
  const float* wq   = (const float*)d_in[1];
  const float* bq   = (const float*)d_in[2];
  const float* wk   = (const float*)d_in[3];
  const float* bk   = (const float*)d_in[4];
  const float* wv   = (const float*)d_in[5];
  const float* bv   = (const float*)d_in[6];
  const float* wo   = (const float*)d_in[7];
  const float* cosd = (const float*)d_in[8];
  const float* sind = (const float*)d_in[9];
  float* out = (float*)d_out;

  float* qb = (float*)d_ws;                    // SEQ*HID        = 7.34M floats
  float* kb = qb + (size_t)SEQ * NH * HD;      // SEQ*512
  float* vb = kb + (size_t)SEQ * NKV * HD;     // SEQ*512
  float* ao = vb + (size_t)SEQ * NKV * HD;     // SEQ*HID

  dim3 blk(256);
  // Q/K/V projections
  gemm_bias_f32<<<dim3(HID / 64, SEQ / 64), blk, 0, stream>>>(x, wq, bq, qb, SEQ, NH * HD, HID);
  gemm_bias_f32<<<dim3((NKV * HD) / 64, SEQ / 64), blk, 0, stream>>>(x, wk, bk, kb, SEQ, NKV * HD, HID);
  gemm_bias_f32<<<dim3((NKV * HD) / 64, SEQ / 64), blk, 0, stream>>>(x, wv, bv, vb, SEQ, NKV * HD, HID);
  // RoPE
  rope_kernel<<<dim3(SEQ, NH), dim3(64), 0, stream>>>(qb, cosd, sind, NH);
  rope_kernel<<<dim3(SEQ, NKV), dim3(64), 0, stream>>>(kb, cosd, sind, NKV);
  // attention
  attn_kernel<<<dim3(SEQ / 64, NH), blk, 0, stream>>>(qb, kb, vb, ao);
  // output projection
  gemm_bias_f32<<<dim3(HID / 64, SEQ / 64), blk, 0, stream>>>(ao, wo, nullptr, out, SEQ, HID, HID);
}

// Round 2
// 566.466 us; speedup vs baseline: 14.1631x; 14.1631x over previous
//
#include <hip/hip_runtime.h>
#include <math.h>

#define SEQ 2048
#define HID 3584
#define NH 28
#define NKV 4
#define HD 128
#define GQA (NH / NKV)

typedef __attribute__((ext_vector_type(8))) short short8;
typedef __attribute__((ext_vector_type(4))) float f32x4;
typedef unsigned int u32;
typedef unsigned short ushort_t;

__device__ inline ushort_t f2bf(float f) {
  u32 x = __float_as_uint(f);
  return (ushort_t)((x + 0x7FFFu + ((x >> 16) & 1u)) >> 16);
}
__device__ inline float bf2f(ushort_t h) {
  return __uint_as_float(((u32)h) << 16);
}
__device__ inline void gload16(const void* g, void* l) {
  __builtin_amdgcn_global_load_lds((const u32 __attribute__((address_space(1)))*)g,
                                   (u32 __attribute__((address_space(3)))*)l, 16, 0, 0);
}

// ---------------- cast x -> bf16 ----------------
__global__ __launch_bounds__(256) void cast_bf16_kernel(const float* __restrict__ in,
                                                        ushort_t* __restrict__ out, int n4) {
  int i = blockIdx.x * blockDim.x + threadIdx.x;
  if (i >= n4) return;
  float4 v = ((const float4*)in)[i];
  ushort4 o;
  o.x = f2bf(v.x); o.y = f2bf(v.y); o.z = f2bf(v.z); o.w = f2bf(v.w);
  *(ushort4*)&out[(size_t)i * 4] = o;
}

// ---------------- transpose-cast: in [K][N] f32 -> out [N][K] bf16 ----------------
__global__ __launch_bounds__(256) void transpose_cast_kernel(const float* __restrict__ in,
                                                             ushort_t* __restrict__ out,
                                                             int K, int N) {
  __shared__ ushort_t t[64][65];
  const int bk = blockIdx.y * 64, bn = blockIdx.x * 64;
  const int tid = threadIdx.x;
#pragma unroll
  for (int i = 0; i < 4; i++) {
    int idx = i * 256 + tid;
    int r = idx >> 4, c4 = idx & 15;
    float4 v = *(const float4*)&in[(size_t)(bk + r) * N + bn + c4 * 4];
    t[c4 * 4 + 0][r] = f2bf(v.x);
    t[c4 * 4 + 1][r] = f2bf(v.y);
    t[c4 * 4 + 2][r] = f2bf(v.z);
    t[c4 * 4 + 3][r] = f2bf(v.w);
  }
  __syncthreads();
#pragma unroll
  for (int i = 0; i < 4; i++) {
    int idx = i * 256 + tid;
    int r = idx >> 4, c4 = idx & 15;
    ushort4 o;
    o.x = t[r][c4 * 4 + 0]; o.y = t[r][c4 * 4 + 1];
    o.z = t[r][c4 * 4 + 2]; o.w = t[r][c4 * 4 + 3];
    *(ushort4*)&out[(size_t)(bn + r) * K + bk + c4 * 4] = o;
  }
}

// ---------------- bf16 MFMA GEMM ----------------
// C[M][N] = A[M][K] @ BT[N][K]^T (+bias). mode: 0=f32 out, 1=bf16 out, 2=bf16 transposed out
__global__ __launch_bounds__(256) void gemm_mfma(
    const ushort_t* __restrict__ A, const ushort_t* __restrict__ BT,
    const float* __restrict__ bias, float* __restrict__ Cf, ushort_t* __restrict__ Cb,
    int M, int N, int K, int mode) {
  __shared__ __align__(16) ushort_t As[2][128 * 32];
  __shared__ __align__(16) ushort_t Bs[2][128 * 32];
  const int tid = threadIdx.x;
  const int w = tid >> 6, lane = tid & 63;
  const int g = lane >> 4, r16 = lane & 15;
  const int wr = w >> 1, wc = w & 1;
  const int bm = blockIdx.y * 128, bn = blockIdx.x * 128;

  f32x4 acc[4][4];
#pragma unroll
  for (int i = 0; i < 4; i++)
#pragma unroll
    for (int j = 0; j < 4; j++) acc[i][j] = (f32x4){0.f, 0.f, 0.f, 0.f};

  const int nk = K >> 5;
  // prologue stage tile 0
#pragma unroll
  for (int i = 0; i < 2; i++) {
    int gi = i * 256 + w * 64 + lane;
    int row = gi >> 2, gc = gi & 3;
    gload16(&A[(size_t)(bm + row) * K + gc * 8], &As[0][(i * 256 + w * 64) * 8]);
    gload16(&BT[(size_t)(bn + row) * K + gc * 8], &Bs[0][(i * 256 + w * 64) * 8]);
  }
  __syncthreads();

  int buf = 0;
  for (int kt = 0; kt < nk; kt++) {
    if (kt + 1 < nk) {
      const int k0 = (kt + 1) << 5;
#pragma unroll
      for (int i = 0; i < 2; i++) {
        int gi = i * 256 + w * 64 + lane;
        int row = gi >> 2, gc = gi & 3;
        gload16(&A[(size_t)(bm + row) * K + k0 + gc * 8], &As[buf ^ 1][(i * 256 + w * 64) * 8]);
        gload16(&BT[(size_t)(bn + row) * K + k0 + gc * 8], &Bs[buf ^ 1][(i * 256 + w * 64) * 8]);
      }
    }
    short8 af[4], bfr[4];
#pragma unroll
    for (int mi = 0; mi < 4; mi++)
      af[mi] = *(const short8*)&As[buf][((wr * 64 + mi * 16 + r16) * 4 + g) * 8];
#pragma unroll
    for (int ni = 0; ni < 4; ni++)
      bfr[ni] = *(const short8*)&Bs[buf][((wc * 64 + ni * 16 + r16) * 4 + g) * 8];
#pragma unroll
    for (int mi = 0; mi < 4; mi++)
#pragma unroll
      for (int ni = 0; ni < 4; ni++)
        acc[mi][ni] = __builtin_amdgcn_mfma_f32_16x16x32_bf16(af[mi], bfr[ni], acc[mi][ni], 0, 0, 0);
    __syncthreads();  // drains vmcnt(0): next tile staged, this tile's reads done
    buf ^= 1;
  }

#pragma unroll
  for (int mi = 0; mi < 4; mi++)
#pragma unroll
    for (int ni = 0; ni < 4; ni++)
#pragma unroll
      for (int r = 0; r < 4; r++) {
        int row = bm + wr * 64 + mi * 16 + 4 * g + r;
        int col = bn + wc * 64 + ni * 16 + r16;
        float v = acc[mi][ni][r];
        if (bias) v += bias[col];
        if (mode == 0) Cf[(size_t)row * N + col] = v;
        else if (mode == 1) Cb[(size_t)row * N + col] = f2bf(v);
        else Cb[(size_t)col * M + row] = f2bf(v);
      }
}

// ---------------- RoPE in-place on bf16 [S][nheads][128] ----------------
__global__ void rope_kernel(ushort_t* __restrict__ buf, const float* __restrict__ cosd,
                            const float* __restrict__ sind, int nheads) {
  const int s = blockIdx.x, h = blockIdx.y, d = threadIdx.x;  // d: 0..63
  const float c = cosd[s * 64 + d], sn = sind[s * 64 + d];
  ushort_t* p = buf + ((size_t)s * nheads + h) * HD;
  float x1 = bf2f(p[d]), x2 = bf2f(p[d + 64]);
  p[d] = f2bf(x1 * c - x2 * sn);
  p[d + 64] = f2bf(x1 * sn + x2 * c);
}

// ---------------- MFMA causal GQA flash attention ----------------
// q: [S][NH*128], k: [S][NKV*128], vT: [NKV*128][S], out: [S][NH*128]  (all bf16)
__global__ __launch_bounds__(256) void attn_mfma(
    const ushort_t* __restrict__ q, const ushort_t* __restrict__ k,
    const ushort_t* __restrict__ vT, ushort_t* __restrict__ out) {
  const int qt = blockIdx.x, h = blockIdx.y, kvh = h / GQA;
  const int q0 = qt * 64;
  const int tid = threadIdx.x, w = tid >> 6, lane = tid & 63;
  const int g = lane >> 4, r16 = lane & 15;

  __shared__ __align__(16) ushort_t Ks[64 * 128];   // [key][d], granule-swizzled by key&7
  __shared__ __align__(16) ushort_t Vs[128 * 64];   // [d][key], granule-swizzled by d&7
  __shared__ __align__(16) ushort_t Ps[4][16][72];  // per-wave P, padded rows (144 B)

  // Q fragments in registers: rows q0+w*16+r16, k-slices of 32 over d
  short8 qf[4];
  {
    const ushort_t* qp = q + (size_t)(q0 + w * 16 + r16) * (NH * HD) + h * HD;
#pragma unroll
    for (int f = 0; f < 4; f++) qf[f] = *(const short8*)(qp + f * 32 + g * 8);
  }
  float mrow[4], lrow[4];
#pragma unroll
  for (int r = 0; r < 4; r++) { mrow[r] = -1e30f; lrow[r] = 0.f; }
  f32x4 oa[8];
#pragma unroll
  for (int d = 0; d < 8; d++) oa[d] = (f32x4){0.f, 0.f, 0.f, 0.f};

  const float scale = 0.08838834764831845f;
  const int ntiles = qt + 1;

  for (int t = 0; t < ntiles; t++) {
    const int kb = t * 64;
    __syncthreads();  // previous tile's LDS reads done
    // stage K tile: 64 keys x 128 d = 1024 granules of 16B, src pre-swizzled
#pragma unroll
    for (int i = 0; i < 4; i++) {
      int gi = i * 256 + w * 64 + lane;
      int key = gi >> 4, gd = gi & 15;
      int gsrc = gd ^ (key & 7);
      gload16(&k[(size_t)(kb + key) * (NKV * HD) + kvh * HD + gsrc * 8],
              &Ks[(i * 256 + w * 64) * 8]);
    }
    // stage V^T tile: 128 d x 64 keys = 1024 granules
#pragma unroll
    for (int i = 0; i < 4; i++) {
      int gi = i * 256 + w * 64 + lane;
      int d = gi >> 3, gc = gi & 7;
      int gsrc = gc ^ (d & 7);
      gload16(&vT[(size_t)(kvh * HD + d) * SEQ + kb + gsrc * 8],
              &Vs[(i * 256 + w * 64) * 8]);
    }
    __syncthreads();  // drains vmcnt(0)

    // ---- QK^T: S[16 rows][64 keys] per wave ----
    f32x4 sfr[4];
#pragma unroll
    for (int kb4 = 0; kb4 < 4; kb4++) {
      f32x4 acc = (f32x4){0.f, 0.f, 0.f, 0.f};
      const int key = kb4 * 16 + r16;
#pragma unroll
      for (int ks = 0; ks < 4; ks++) {
        short8 kf = *(const short8*)&Ks[key * 128 + (((4 * ks + g) ^ (key & 7)) * 8)];
        acc = __builtin_amdgcn_mfma_f32_16x16x32_bf16(qf[ks], kf, acc, 0, 0, 0);
      }
      sfr[kb4] = acc;
    }
    const bool last = (t == ntiles - 1);
#pragma unroll
    for (int kb4 = 0; kb4 < 4; kb4++)
#pragma unroll
      for (int r = 0; r < 4; r++) {
        float s = sfr[kb4][r] * scale;
        if (last && (kb4 * 16 + r16 > w * 16 + 4 * g + r)) s = -1e30f;
        sfr[kb4][r] = s;
      }
    // ---- online softmax (reduce across the 16 column-lanes of the group) ----
    float pmax[4], resc[4];
#pragma unroll
    for (int r = 0; r < 4; r++) {
      float x = fmaxf(fmaxf(sfr[0][r], sfr[1][r]), fmaxf(sfr[2][r], sfr[3][r]));
      x = fmaxf(x, __shfl_xor(x, 1));
      x = fmaxf(x, __shfl_xor(x, 2));
      x = fmaxf(x, __shfl_xor(x, 4));
      x = fmaxf(x, __shfl_xor(x, 8));
      pmax[r] = x;
    }
#pragma unroll
    for (int r = 0; r < 4; r++) {
      float nm = fmaxf(mrow[r], pmax[r]);
      resc[r] = __expf(mrow[r] - nm);
      mrow[r] = nm;
    }
    float psum[4] = {0.f, 0.f, 0.f, 0.f};
#pragma unroll
    for (int kb4 = 0; kb4 < 4; kb4++)
#pragma unroll
      for (int r = 0; r < 4; r++) {
        float p = __expf(sfr[kb4][r] - mrow[r]);
        psum[r] += p;
        Ps[w][4 * g + r][kb4 * 16 + r16] = f2bf(p);
      }
#pragma unroll
    for (int r = 0; r < 4; r++) {
      float s = psum[r];
      s += __shfl_xor(s, 1); s += __shfl_xor(s, 2);
      s += __shfl_xor(s, 4); s += __shfl_xor(s, 8);
      lrow[r] = lrow[r] * resc[r] + s;
    }
#pragma unroll
    for (int d = 0; d < 8; d++)
#pragma unroll
      for (int r = 0; r < 4; r++) oa[d][r] *= resc[r];

    // ---- PV: O[16][128] += P[16][64] @ V[64][128] ----
    short8 pf[2];
    pf[0] = *(const short8*)&Ps[w][r16][g * 8];
    pf[1] = *(const short8*)&Ps[w][r16][32 + g * 8];
#pragma unroll
    for (int d = 0; d < 8; d++) {
      const int dd = d * 16 + r16;
#pragma unroll
      for (int ks2 = 0; ks2 < 2; ks2++) {
        short8 vf = *(const short8*)&Vs[dd * 64 + (((4 * ks2 + g) ^ (dd & 7)) * 8)];
        oa[d] = __builtin_amdgcn_mfma_f32_16x16x32_bf16(pf[ks2], vf, oa[d], 0, 0, 0);
      }
    }
  }
  // epilogue
#pragma unroll
  for (int d = 0; d < 8; d++)
#pragma unroll
    for (int r = 0; r < 4; r++) {
      int row = q0 + w * 16 + 4 * g + r;
      int col = h * HD + d * 16 + r16;
      out[(size_t)row * (NH * HD) + col] = f2bf(oa[d][r] / lrow[r]);
    }
}

extern "C" void kernel_launch(void* const* d_in, const int* in_sizes, int n_in,
                              void* d_out, int out_size, void* d_ws, size_t ws_size,
                              hipStream_t stream) {
  const float* x    = (const float*)d_in[0];
  const float* wq   = (const float*)d_in[1];
  const float* bq   = (const float*)d_in[2];
  const float* wk   = (const float*)d_in[3];
  const float* bk   = (const float*)d_in[4];
  const float* wv   = (const float*)d_in[5];
  const float* bv   = (const float*)d_in[6];
  const float* wo   = (const float*)d_in[7];
  const float* cosd = (const float*)d_in[8];
  const float* sind = (const float*)d_in[9];
  float* out = (float*)d_out;

  ushort_t* ws  = (ushort_t*)d_ws;
  ushort_t* wT0 = ws;                                   // [3584][3584] wq^T, later wo^T
  ushort_t* wkT = wT0 + (size_t)HID * HID;              // [512][3584]
  ushort_t* wvT = wkT + (size_t)(NKV * HD) * HID;       // [512][3584]
  ushort_t* xb  = wvT + (size_t)(NKV * HD) * HID;       // [2048][3584] (reused as attn out)
  ushort_t* qb  = xb + (size_t)SEQ * HID;               // [2048][3584]
  ushort_t* kb_ = qb + (size_t)SEQ * HID;               // [2048][512]
  ushort_t* vbT = kb_ + (size_t)SEQ * (NKV * HD);       // [512][2048]
  ushort_t* aob = xb;                                   // reuse (x no longer needed)

  // 1. cast x -> bf16
  cast_bf16_kernel<<<(SEQ * HID / 4) / 256, 256, 0, stream>>>(x, xb, SEQ * HID / 4);
  // 2. Q projection
  transpose_cast_kernel<<<dim3(HID / 64, HID / 64), 256, 0, stream>>>(wq, wT0, HID, HID);
  gemm_mfma<<<dim3(HID / 128, SEQ / 128), 256, 0, stream>>>(xb, wT0, bq, nullptr, qb, SEQ, HID, HID, 1);
  // 3. K projection
  transpose_cast_kernel<<<dim3((NKV * HD) / 64, HID / 64), 256, 0, stream>>>(wk, wkT, HID, NKV * HD);
  gemm_mfma<<<dim3((NKV * HD) / 128, SEQ / 128), 256, 0, stream>>>(xb, wkT, bk, nullptr, kb_, SEQ, NKV * HD, HID, 1);
  // 4. V projection (transposed output)
  transpose_cast_kernel<<<dim3((NKV * HD) / 64, HID / 64), 256, 0, stream>>>(wv, wvT, HID, NKV * HD);
  gemm_mfma<<<dim3((NKV * HD) / 128, SEQ / 128), 256, 0, stream>>>(xb, wvT, bv, nullptr, vbT, SEQ, NKV * HD, HID, 2);
  // 5. RoPE on q, k
  rope_kernel<<<dim3(SEQ, NH), 64, 0, stream>>>(qb, cosd, sind, NH);
  rope_kernel<<<dim3(SEQ, NKV), 64, 0, stream>>>(kb_, cosd, sind, NKV);
  // 6. attention
  attn_mfma<<<dim3(SEQ / 64, NH), 256, 0, stream>>>(qb, kb_, vbT, aob);
  // 7. output projection (fp32 out, no bias)
  transpose_cast_kernel<<<dim3(HID / 64, HID / 64), 256, 0, stream>>>(wo, wT0, HID, HID);
  gemm_mfma<<<dim3(HID / 128, SEQ / 128), 256, 0, stream>>>(aob, wT0, nullptr, out, nullptr, SEQ, HID, HID, 0);
}

// Round 3
// 495.459 us; speedup vs baseline: 16.1929x; 1.1433x over previous
//
#include <hip/hip_runtime.h>
#include <math.h>

#define SEQ 2048
#define HID 3584
#define NH 28
#define NKV 4
#define HD 128
#define GQA (NH / NKV)
#define NQKV (NH * HD + 2 * NKV * HD)  // 4608

typedef __attribute__((ext_vector_type(8))) short short8;
typedef __attribute__((ext_vector_type(4))) float f32x4;
typedef unsigned int u32;
typedef unsigned short ushort_t;

__device__ inline ushort_t f2bf(float f) {
  u32 x = __float_as_uint(f);
  return (ushort_t)((x + 0x7FFFu + ((x >> 16) & 1u)) >> 16);
}
__device__ inline float bf2f(ushort_t h) {
  return __uint_as_float(((u32)h) << 16);
}
__device__ inline void gload16(const void* g, void* l) {
  __builtin_amdgcn_global_load_lds((const u32 __attribute__((address_space(1)))*)g,
                                   (u32 __attribute__((address_space(3)))*)l, 16, 0, 0);
}

// ---------------- cast x -> bf16 ----------------
__global__ __launch_bounds__(256) void cast_bf16_kernel(const float* __restrict__ in,
                                                        ushort_t* __restrict__ out, int n4) {
  int i = blockIdx.x * blockDim.x + threadIdx.x;
  if (i >= n4) return;
  float4 v = ((const float4*)in)[i];
  ushort4 o;
  o.x = f2bf(v.x); o.y = f2bf(v.y); o.z = f2bf(v.z); o.w = f2bf(v.w);
  *(ushort4*)&out[(size_t)i * 4] = o;
}

// ---------------- transpose-cast: in [K][N] f32 -> out [N][K] bf16 ----------------
__global__ __launch_bounds__(256) void transpose_cast_kernel(const float* __restrict__ in,
                                                             ushort_t* __restrict__ out,
                                                             int K, int N) {
  __shared__ ushort_t t[64][65];
  const int bk = blockIdx.y * 64, bn = blockIdx.x * 64;
  const int tid = threadIdx.x;
#pragma unroll
  for (int i = 0; i < 4; i++) {
    int idx = i * 256 + tid;
    int r = idx >> 4, c4 = idx & 15;
    float4 v = *(const float4*)&in[(size_t)(bk + r) * N + bn + c4 * 4];
    t[c4 * 4 + 0][r] = f2bf(v.x);
    t[c4 * 4 + 1][r] = f2bf(v.y);
    t[c4 * 4 + 2][r] = f2bf(v.z);
    t[c4 * 4 + 3][r] = f2bf(v.w);
  }
  __syncthreads();
#pragma unroll
  for (int i = 0; i < 4; i++) {
    int idx = i * 256 + tid;
    int r = idx >> 4, c4 = idx & 15;
    ushort4 o;
    o.x = t[r][c4 * 4 + 0]; o.y = t[r][c4 * 4 + 1];
    o.z = t[r][c4 * 4 + 2]; o.w = t[r][c4 * 4 + 3];
    *(ushort4*)&out[(size_t)(bn + r) * K + bk + c4 * 4] = o;
  }
}

// ---------------- bf16 MFMA GEMM ----------------
// C[M][N] = A[M][K] @ BT[N][K]^T (+bias).
// mode 0: f32 out (Cf). mode 1: bf16 out (Cb).
// mode 3: fused QKV routing: cols [0,3584)->Cb (q), [3584,4096)->Ck (k),
//         [4096,4608)->Cv transposed (vT). biases bq/bk2/bv2.
__global__ __launch_bounds__(256) void gemm_mfma(
    const ushort_t* __restrict__ A, const ushort_t* __restrict__ BT,
    const float* __restrict__ bias, float* __restrict__ Cf, ushort_t* __restrict__ Cb,
    ushort_t* __restrict__ Ck, ushort_t* __restrict__ Cv,
    const float* __restrict__ bias_k, const float* __restrict__ bias_v,
    int M, int N, int K, int mode) {
  __shared__ __align__(16) ushort_t As[2][128 * 32];
  __shared__ __align__(16) ushort_t Bs[2][128 * 32];
  const int tid = threadIdx.x;
  const int w = tid >> 6, lane = tid & 63;
  const int g = lane >> 4, r16 = lane & 15;
  const int wr = w >> 1, wc = w & 1;
  const int bm = blockIdx.y * 128, bn = blockIdx.x * 128;

  f32x4 acc[4][4];
#pragma unroll
  for (int i = 0; i < 4; i++)
#pragma unroll
    for (int j = 0; j < 4; j++) acc[i][j] = (f32x4){0.f, 0.f, 0.f, 0.f};

  const int nk = K >> 5;
#pragma unroll
  for (int i = 0; i < 2; i++) {
    int gi = i * 256 + w * 64 + lane;
    int row = gi >> 2, gc = gi & 3;
    gload16(&A[(size_t)(bm + row) * K + gc * 8], &As[0][(i * 256 + w * 64) * 8]);
    gload16(&BT[(size_t)(bn + row) * K + gc * 8], &Bs[0][(i * 256 + w * 64) * 8]);
  }
  __syncthreads();

  int buf = 0;
  for (int kt = 0; kt < nk; kt++) {
    if (kt + 1 < nk) {
      const int k0 = (kt + 1) << 5;
#pragma unroll
      for (int i = 0; i < 2; i++) {
        int gi = i * 256 + w * 64 + lane;
        int row = gi >> 2, gc = gi & 3;
        gload16(&A[(size_t)(bm + row) * K + k0 + gc * 8], &As[buf ^ 1][(i * 256 + w * 64) * 8]);
        gload16(&BT[(size_t)(bn + row) * K + k0 + gc * 8], &Bs[buf ^ 1][(i * 256 + w * 64) * 8]);
      }
    }
    short8 af[4], bfr[4];
#pragma unroll
    for (int mi = 0; mi < 4; mi++)
      af[mi] = *(const short8*)&As[buf][((wr * 64 + mi * 16 + r16) * 4 + g) * 8];
#pragma unroll
    for (int ni = 0; ni < 4; ni++)
      bfr[ni] = *(const short8*)&Bs[buf][((wc * 64 + ni * 16 + r16) * 4 + g) * 8];
    __builtin_amdgcn_s_setprio(1);
#pragma unroll
    for (int mi = 0; mi < 4; mi++)
#pragma unroll
      for (int ni = 0; ni < 4; ni++)
        acc[mi][ni] = __builtin_amdgcn_mfma_f32_16x16x32_bf16(af[mi], bfr[ni], acc[mi][ni], 0, 0, 0);
    __builtin_amdgcn_s_setprio(0);
    __syncthreads();
    buf ^= 1;
  }

  if (mode == 3) {
    // block-uniform region select (3584 and 4096 are multiples of 128)
#pragma unroll
    for (int mi = 0; mi < 4; mi++)
#pragma unroll
      for (int ni = 0; ni < 4; ni++)
#pragma unroll
        for (int r = 0; r < 4; r++) {
          int row = bm + wr * 64 + mi * 16 + 4 * g + r;
          int col = bn + wc * 64 + ni * 16 + r16;
          float v = acc[mi][ni][r];
          if (bn < NH * HD) {
            Cb[(size_t)row * (NH * HD) + col] = f2bf(v + bias[col]);
          } else if (bn < NH * HD + NKV * HD) {
            int c = col - NH * HD;
            Ck[(size_t)row * (NKV * HD) + c] = f2bf(v + bias_k[c]);
          } else {
            int c = col - (NH * HD + NKV * HD);
            Cv[(size_t)c * M + row] = f2bf(v + bias_v[c]);
          }
        }
    return;
  }
#pragma unroll
  for (int mi = 0; mi < 4; mi++)
#pragma unroll
    for (int ni = 0; ni < 4; ni++)
#pragma unroll
      for (int r = 0; r < 4; r++) {
        int row = bm + wr * 64 + mi * 16 + 4 * g + r;
        int col = bn + wc * 64 + ni * 16 + r16;
        float v = acc[mi][ni][r];
        if (bias) v += bias[col];
        if (mode == 0) Cf[(size_t)row * N + col] = v;
        else Cb[(size_t)row * N + col] = f2bf(v);
      }
}

// ---------------- RoPE in-place on bf16 [S][nheads][128] ----------------
__global__ void rope_kernel(ushort_t* __restrict__ buf, const float* __restrict__ cosd,
                            const float* __restrict__ sind, int nheads) {
  const int s = blockIdx.x, h = blockIdx.y, d = threadIdx.x;  // d: 0..63
  const float c = cosd[s * 64 + d], sn = sind[s * 64 + d];
  ushort_t* p = buf + ((size_t)s * nheads + h) * HD;
  float x1 = bf2f(p[d]), x2 = bf2f(p[d + 64]);
  p[d] = f2bf(x1 * c - x2 * sn);
  p[d + 64] = f2bf(x1 * sn + x2 * c);
}

// ---------------- MFMA causal GQA flash attention ----------------
// q: [S][NH*128], k: [S][NKV*128], vT: [NKV*128][S], out: [S][NH*128]  (all bf16)
// 128 q-rows per block, 4 waves x 32 rows (two 16-row fragments).
__global__ __launch_bounds__(256) void attn_mfma(
    const ushort_t* __restrict__ q, const ushort_t* __restrict__ k,
    const ushort_t* __restrict__ vT, ushort_t* __restrict__ out) {
  const int qt = (SEQ / 128 - 1) - blockIdx.x;  // longest blocks first
  const int h = blockIdx.y, kvh = h / GQA;
  const int q0 = qt * 128;
  const int tid = threadIdx.x, w = tid >> 6, lane = tid & 63;
  const int g = lane >> 4, r16 = lane & 15;

  __shared__ __align__(16) ushort_t Ks[64 * 128];   // [key][d], granule-swizzled by key&7
  __shared__ __align__(16) ushort_t Vs[128 * 64];   // [d][key], granule-swizzled by d&7
  __shared__ __align__(16) ushort_t Ps[4][32][72];  // per-wave P

  short8 qf[2][4];
#pragma unroll
  for (int m = 0; m < 2; m++) {
    const ushort_t* qp = q + (size_t)(q0 + w * 32 + m * 16 + r16) * (NH * HD) + h * HD;
#pragma unroll
    for (int f = 0; f < 4; f++) qf[m][f] = *(const short8*)(qp + f * 32 + g * 8);
  }
  float mrow[2][4], lrow[2][4];
#pragma unroll
  for (int m = 0; m < 2; m++)
#pragma unroll
    for (int r = 0; r < 4; r++) { mrow[m][r] = -1e30f; lrow[m][r] = 0.f; }
  f32x4 oa[2][8];
#pragma unroll
  for (int m = 0; m < 2; m++)
#pragma unroll
    for (int d = 0; d < 8; d++) oa[m][d] = (f32x4){0.f, 0.f, 0.f, 0.f};

  const float scale = 0.08838834764831845f;
  const int ntiles = 2 * qt + 2;

  for (int t = 0; t < ntiles; t++) {
    const int kb = t * 64;
    __syncthreads();
#pragma unroll
    for (int i = 0; i < 4; i++) {
      int gi = i * 256 + w * 64 + lane;
      int key = gi >> 4, gd = gi & 15;
      int gsrc = gd ^ (key & 7);
      gload16(&k[(size_t)(kb + key) * (NKV * HD) + kvh * HD + gsrc * 8],
              &Ks[(i * 256 + w * 64) * 8]);
    }
#pragma unroll
    for (int i = 0; i < 4; i++) {
      int gi = i * 256 + w * 64 + lane;
      int d = gi >> 3, gc = gi & 7;
      int gsrc = gc ^ (d & 7);
      gload16(&vT[(size_t)(kvh * HD + d) * SEQ + kb + gsrc * 8],
              &Vs[(i * 256 + w * 64) * 8]);
    }
    __syncthreads();

    const bool tail = (kb + 64 > q0);  // only last two tiles need masking
#pragma unroll
    for (int m = 0; m < 2; m++) {
      const int rbase = q0 + w * 32 + m * 16;
      if (kb > rbase + 15) continue;  // fragment fully masked

      // ---- QK^T: S[16 rows][64 keys] ----
      f32x4 sfr[4];
      __builtin_amdgcn_s_setprio(1);
#pragma unroll
      for (int kb4 = 0; kb4 < 4; kb4++) {
        f32x4 acc = (f32x4){0.f, 0.f, 0.f, 0.f};
        const int key = kb4 * 16 + r16;
#pragma unroll
        for (int ks = 0; ks < 4; ks++) {
          short8 kf = *(const short8*)&Ks[key * 128 + (((4 * ks + g) ^ (key & 7)) * 8)];
          acc = __builtin_amdgcn_mfma_f32_16x16x32_bf16(qf[m][ks], kf, acc, 0, 0, 0);
        }
        sfr[kb4] = acc;
      }
      __builtin_amdgcn_s_setprio(0);
#pragma unroll
      for (int kb4 = 0; kb4 < 4; kb4++)
#pragma unroll
        for (int r = 0; r < 4; r++) {
          float s = sfr[kb4][r] * scale;
          if (tail && (kb + kb4 * 16 + r16 > rbase + 4 * g + r)) s = -1e30f;
          sfr[kb4][r] = s;
        }
      // ---- online softmax ----
      float pmax[4], resc[4];
#pragma unroll
      for (int r = 0; r < 4; r++) {
        float x = fmaxf(fmaxf(sfr[0][r], sfr[1][r]), fmaxf(sfr[2][r], sfr[3][r]));
        x = fmaxf(x, __shfl_xor(x, 1));
        x = fmaxf(x, __shfl_xor(x, 2));
        x = fmaxf(x, __shfl_xor(x, 4));
        x = fmaxf(x, __shfl_xor(x, 8));
        pmax[r] = x;
      }
#pragma unroll
      for (int r = 0; r < 4; r++) {
        float nm = fmaxf(mrow[m][r], pmax[r]);
        resc[r] = __expf(mrow[m][r] - nm);
        mrow[m][r] = nm;
      }
      float psum[4] = {0.f, 0.f, 0.f, 0.f};
#pragma unroll
      for (int kb4 = 0; kb4 < 4; kb4++)
#pragma unroll
        for (int r = 0; r < 4; r++) {
          float p = __expf(sfr[kb4][r] - mrow[m][r]);
          psum[r] += p;
          Ps[w][m * 16 + 4 * g + r][kb4 * 16 + r16] = f2bf(p);
        }
#pragma unroll
      for (int r = 0; r < 4; r++) {
        float s = psum[r];
        s += __shfl_xor(s, 1); s += __shfl_xor(s, 2);
        s += __shfl_xor(s, 4); s += __shfl_xor(s, 8);
        lrow[m][r] = lrow[m][r] * resc[r] + s;
      }
#pragma unroll
      for (int d = 0; d < 8; d++)
#pragma unroll
        for (int r = 0; r < 4; r++) oa[m][d][r] *= resc[r];

      // ---- PV: O[16][128] += P[16][64] @ V[64][128] ----
      short8 pf[2];
      pf[0] = *(const short8*)&Ps[w][m * 16 + r16][g * 8];
      pf[1] = *(const short8*)&Ps[w][m * 16 + r16][32 + g * 8];
      __builtin_amdgcn_s_setprio(1);
#pragma unroll
      for (int d = 0; d < 8; d++) {
        const int dd = d * 16 + r16;
#pragma unroll
        for (int ks2 = 0; ks2 < 2; ks2++) {
          short8 vf = *(const short8*)&Vs[dd * 64 + (((4 * ks2 + g) ^ (dd & 7)) * 8)];
          oa[m][d] = __builtin_amdgcn_mfma_f32_16x16x32_bf16(pf[ks2], vf, oa[m][d], 0, 0, 0);
        }
      }
      __builtin_amdgcn_s_setprio(0);
    }
  }
  // epilogue
#pragma unroll
  for (int m = 0; m < 2; m++)
#pragma unroll
    for (int d = 0; d < 8; d++)
#pragma unroll
      for (int r = 0; r < 4; r++) {
        int row = q0 + w * 32 + m * 16 + 4 * g + r;
        int col = h * HD + d * 16 + r16;
        out[(size_t)row * (NH * HD) + col] = f2bf(oa[m][d][r] / lrow[m][r]);
      }
}

extern "C" void kernel_launch(void* const* d_in, const int* in_sizes, int n_in,
                              void* d_out, int out_size, void* d_ws, size_t ws_size,
                              hipStream_t stream) {
  const float* x    = (const float*)d_in[0];
  const float* wq   = (const float*)d_in[1];
  const float* bq   = (const float*)d_in[2];
  const float* wk   = (const float*)d_in[3];
  const float* bk   = (const float*)d_in[4];
  const float* wv   = (const float*)d_in[5];
  const float* bv   = (const float*)d_in[6];
  const float* wo   = (const float*)d_in[7];
  const float* cosd = (const float*)d_in[8];
  const float* sind = (const float*)d_in[9];
  float* out = (float*)d_out;

  ushort_t* ws   = (ushort_t*)d_ws;
  ushort_t* wT   = ws;                              // [4608][3584] qkv^T; later wo^T
  ushort_t* xb   = wT + (size_t)NQKV * HID;         // [2048][3584] (later attn out)
  ushort_t* qb   = xb + (size_t)SEQ * HID;          // [2048][3584]
  ushort_t* kb_  = qb + (size_t)SEQ * HID;          // [2048][512]
  ushort_t* vbT  = kb_ + (size_t)SEQ * (NKV * HD);  // [512][2048]
  ushort_t* aob  = xb;                              // reuse after QKV GEMM

  // 1. cast x -> bf16
  cast_bf16_kernel<<<(SEQ * HID / 4) / 256, 256, 0, stream>>>(x, xb, SEQ * HID / 4);
  // 2. transpose-cast weights into fused [4608][3584]
  transpose_cast_kernel<<<dim3(HID / 64, HID / 64), 256, 0, stream>>>(wq, wT, HID, HID);
  transpose_cast_kernel<<<dim3((NKV * HD) / 64, HID / 64), 256, 0, stream>>>(
      wk, wT + (size_t)(NH * HD) * HID, HID, NKV * HD);
  transpose_cast_kernel<<<dim3((NKV * HD) / 64, HID / 64), 256, 0, stream>>>(
      wv, wT + (size_t)(NH * HD + NKV * HD) * HID, HID, NKV * HD);
  // 3. fused QKV projection
  gemm_mfma<<<dim3(NQKV / 128, SEQ / 128), 256, 0, stream>>>(
      xb, wT, bq, nullptr, qb, kb_, vbT, bk, bv, SEQ, NQKV, HID, 3);
  // 4. RoPE on q, k
  rope_kernel<<<dim3(SEQ, NH), 64, 0, stream>>>(qb, cosd, sind, NH);
  rope_kernel<<<dim3(SEQ, NKV), 64, 0, stream>>>(kb_, cosd, sind, NKV);
  // 5. attention
  attn_mfma<<<dim3(SEQ / 128, NH), 256, 0, stream>>>(qb, kb_, vbT, aob);
  // 6. output projection (reuse wT region for wo^T)
  transpose_cast_kernel<<<dim3(HID / 64, HID / 64), 256, 0, stream>>>(wo, wT, HID, HID);
  gemm_mfma<<<dim3(HID / 128, SEQ / 128), 256, 0, stream>>>(
      aob, wT, nullptr, out, nullptr, nullptr, nullptr, nullptr, nullptr, SEQ, HID, HID, 0);
}

// Round 4
// 487.422 us; speedup vs baseline: 16.4599x; 1.0165x over previous
//
#include <hip/hip_runtime.h>
#include <math.h>

#define SEQ 2048
#define HID 3584
#define NH 28
#define NKV 4
#define HD 128
#define GQA (NH / NKV)
#define NQKV (NH * HD + 2 * NKV * HD)  // 4608

typedef __attribute__((ext_vector_type(8))) short short8;
typedef __attribute__((ext_vector_type(4))) float f32x4;
typedef unsigned int u32;
typedef unsigned short ushort_t;

__device__ inline ushort_t f2bf(float f) {
  u32 x = __float_as_uint(f);
  return (ushort_t)((x + 0x7FFFu + ((x >> 16) & 1u)) >> 16);
}
__device__ inline float bf2f(ushort_t h) {
  return __uint_as_float(((u32)h) << 16);
}
__device__ inline void gload16(const void* g, void* l) {
  __builtin_amdgcn_global_load_lds((const u32 __attribute__((address_space(1)))*)g,
                                   (u32 __attribute__((address_space(3)))*)l, 16, 0, 0);
}

// ---------------- cast x -> bf16 ----------------
__global__ __launch_bounds__(256) void cast_bf16_kernel(const float* __restrict__ in,
                                                        ushort_t* __restrict__ out, int n4) {
  int i = blockIdx.x * blockDim.x + threadIdx.x;
  if (i >= n4) return;
  float4 v = ((const float4*)in)[i];
  ushort4 o;
  o.x = f2bf(v.x); o.y = f2bf(v.y); o.z = f2bf(v.z); o.w = f2bf(v.w);
  *(ushort4*)&out[(size_t)i * 4] = o;
}

// ---------------- transpose-cast: in [K][N] f32 -> out [N][K] bf16 ----------------
__global__ __launch_bounds__(256) void transpose_cast_kernel(const float* __restrict__ in,
                                                             ushort_t* __restrict__ out,
                                                             int K, int N) {
  __shared__ ushort_t t[64][65];
  const int bk = blockIdx.y * 64, bn = blockIdx.x * 64;
  const int tid = threadIdx.x;
#pragma unroll
  for (int i = 0; i < 4; i++) {
    int idx = i * 256 + tid;
    int r = idx >> 4, c4 = idx & 15;
    float4 v = *(const float4*)&in[(size_t)(bk + r) * N + bn + c4 * 4];
    t[c4 * 4 + 0][r] = f2bf(v.x);
    t[c4 * 4 + 1][r] = f2bf(v.y);
    t[c4 * 4 + 2][r] = f2bf(v.z);
    t[c4 * 4 + 3][r] = f2bf(v.w);
  }
  __syncthreads();
#pragma unroll
  for (int i = 0; i < 4; i++) {
    int idx = i * 256 + tid;
    int r = idx >> 4, c4 = idx & 15;
    ushort4 o;
    o.x = t[r][c4 * 4 + 0]; o.y = t[r][c4 * 4 + 1];
    o.z = t[r][c4 * 4 + 2]; o.w = t[r][c4 * 4 + 3];
    *(ushort4*)&out[(size_t)(bn + r) * K + bk + c4 * 4] = o;
  }
}

// ---------------- bf16 MFMA GEMM ----------------
// C[M][N] = A[M][K] @ BT[N][K]^T (+bias).
// mode 0: f32 out (Cf). mode 1: bf16 out (Cb).
// mode 3: fused QKV routing: cols [0,3584)->Cb (q), [3584,4096)->Ck (k),
//         [4096,4608)->Cv transposed (vT).
__global__ __launch_bounds__(256) void gemm_mfma(
    const ushort_t* __restrict__ A, const ushort_t* __restrict__ BT,
    const float* __restrict__ bias, float* __restrict__ Cf, ushort_t* __restrict__ Cb,
    ushort_t* __restrict__ Ck, ushort_t* __restrict__ Cv,
    const float* __restrict__ bias_k, const float* __restrict__ bias_v,
    int M, int N, int K, int mode) {
  __shared__ __align__(16) ushort_t As[2][128 * 32];
  __shared__ __align__(16) ushort_t Bs[2][128 * 32];
  const int tid = threadIdx.x;
  const int w = tid >> 6, lane = tid & 63;
  const int g = lane >> 4, r16 = lane & 15;
  const int wr = w >> 1, wc = w & 1;
  const int bm = blockIdx.y * 128, bn = blockIdx.x * 128;

  f32x4 acc[4][4];
#pragma unroll
  for (int i = 0; i < 4; i++)
#pragma unroll
    for (int j = 0; j < 4; j++) acc[i][j] = (f32x4){0.f, 0.f, 0.f, 0.f};

  const int nk = K >> 5;
#pragma unroll
  for (int i = 0; i < 2; i++) {
    int gi = i * 256 + w * 64 + lane;
    int row = gi >> 2, gc = gi & 3;
    gload16(&A[(size_t)(bm + row) * K + gc * 8], &As[0][(i * 256 + w * 64) * 8]);
    gload16(&BT[(size_t)(bn + row) * K + gc * 8], &Bs[0][(i * 256 + w * 64) * 8]);
  }
  __syncthreads();

  int buf = 0;
  for (int kt = 0; kt < nk; kt++) {
    if (kt + 1 < nk) {
      const int k0 = (kt + 1) << 5;
#pragma unroll
      for (int i = 0; i < 2; i++) {
        int gi = i * 256 + w * 64 + lane;
        int row = gi >> 2, gc = gi & 3;
        gload16(&A[(size_t)(bm + row) * K + k0 + gc * 8], &As[buf ^ 1][(i * 256 + w * 64) * 8]);
        gload16(&BT[(size_t)(bn + row) * K + k0 + gc * 8], &Bs[buf ^ 1][(i * 256 + w * 64) * 8]);
      }
    }
    short8 af[4], bfr[4];
#pragma unroll
    for (int mi = 0; mi < 4; mi++)
      af[mi] = *(const short8*)&As[buf][((wr * 64 + mi * 16 + r16) * 4 + g) * 8];
#pragma unroll
    for (int ni = 0; ni < 4; ni++)
      bfr[ni] = *(const short8*)&Bs[buf][((wc * 64 + ni * 16 + r16) * 4 + g) * 8];
    __builtin_amdgcn_s_setprio(1);
#pragma unroll
    for (int mi = 0; mi < 4; mi++)
#pragma unroll
      for (int ni = 0; ni < 4; ni++)
        acc[mi][ni] = __builtin_amdgcn_mfma_f32_16x16x32_bf16(af[mi], bfr[ni], acc[mi][ni], 0, 0, 0);
    __builtin_amdgcn_s_setprio(0);
    __syncthreads();
    buf ^= 1;
  }

  if (mode == 3) {
#pragma unroll
    for (int mi = 0; mi < 4; mi++)
#pragma unroll
      for (int ni = 0; ni < 4; ni++)
#pragma unroll
        for (int r = 0; r < 4; r++) {
          int row = bm + wr * 64 + mi * 16 + 4 * g + r;
          int col = bn + wc * 64 + ni * 16 + r16;
          float v = acc[mi][ni][r];
          if (bn < NH * HD) {
            Cb[(size_t)row * (NH * HD) + col] = f2bf(v + bias[col]);
          } else if (bn < NH * HD + NKV * HD) {
            int c = col - NH * HD;
            Ck[(size_t)row * (NKV * HD) + c] = f2bf(v + bias_k[c]);
          } else {
            int c = col - (NH * HD + NKV * HD);
            Cv[(size_t)c * M + row] = f2bf(v + bias_v[c]);
          }
        }
    return;
  }
#pragma unroll
  for (int mi = 0; mi < 4; mi++)
#pragma unroll
    for (int ni = 0; ni < 4; ni++)
#pragma unroll
      for (int r = 0; r < 4; r++) {
        int row = bm + wr * 64 + mi * 16 + 4 * g + r;
        int col = bn + wc * 64 + ni * 16 + r16;
        float v = acc[mi][ni][r];
        if (bias) v += bias[col];
        if (mode == 0) Cf[(size_t)row * N + col] = v;
        else Cb[(size_t)row * N + col] = f2bf(v);
      }
}

// ---------------- RoPE in-place on bf16 [S][nheads][128] ----------------
__global__ void rope_kernel(ushort_t* __restrict__ buf, const float* __restrict__ cosd,
                            const float* __restrict__ sind, int nheads) {
  const int s = blockIdx.x, h = blockIdx.y, d = threadIdx.x;  // d: 0..63
  const float c = cosd[s * 64 + d], sn = sind[s * 64 + d];
  ushort_t* p = buf + ((size_t)s * nheads + h) * HD;
  float x1 = bf2f(p[d]), x2 = bf2f(p[d + 64]);
  p[d] = f2bf(x1 * c - x2 * sn);
  p[d + 64] = f2bf(x1 * sn + x2 * c);
}

// ---------------- MFMA causal GQA flash attention (2-phase prefetch) ----------------
// q: [S][NH*128], k: [S][NKV*128], vT: [NKV*128][S], out: [S][NH*128]  (all bf16)
// 128 q-rows per block, 4 waves x 32 rows (two 16-row fragments),
// double-buffered K/V staged via global_load_lds, one barrier per tile.
__global__ __launch_bounds__(256) void attn_mfma(
    const ushort_t* __restrict__ q, const ushort_t* __restrict__ k,
    const ushort_t* __restrict__ vT, ushort_t* __restrict__ out) {
  const int qt = (SEQ / 128 - 1) - blockIdx.x;  // longest blocks first
  const int h = blockIdx.y, kvh = h / GQA;
  const int q0 = qt * 128;
  const int tid = threadIdx.x, w = tid >> 6, lane = tid & 63;
  const int g = lane >> 4, r16 = lane & 15;

  __shared__ __align__(16) ushort_t Ks[2][64 * 128];  // [key][d], granule-swizzled by key&7
  __shared__ __align__(16) ushort_t Vs[2][128 * 64];  // [d][key], granule-swizzled by d&7
  __shared__ __align__(16) ushort_t Ps[4][16][72];    // per-wave P (16 rows, per-m reuse)

  short8 qf[2][4];
#pragma unroll
  for (int m = 0; m < 2; m++) {
    const ushort_t* qp = q + (size_t)(q0 + w * 32 + m * 16 + r16) * (NH * HD) + h * HD;
#pragma unroll
    for (int f = 0; f < 4; f++) qf[m][f] = *(const short8*)(qp + f * 32 + g * 8);
  }
  float mrow[2][4], lrow[2][4];
#pragma unroll
  for (int m = 0; m < 2; m++)
#pragma unroll
    for (int r = 0; r < 4; r++) { mrow[m][r] = -1e30f; lrow[m][r] = 0.f; }
  f32x4 oa[2][8];
#pragma unroll
  for (int m = 0; m < 2; m++)
#pragma unroll
    for (int d = 0; d < 8; d++) oa[m][d] = (f32x4){0.f, 0.f, 0.f, 0.f};

  const float scale = 0.08838834764831845f;
  const int ntiles = 2 * qt + 2;

#define STAGE(BUF, T)                                                                   \
  do {                                                                                  \
    const int kb_ = (T) * 64;                                                           \
    _Pragma("unroll") for (int i = 0; i < 4; i++) {                                     \
      int gi = i * 256 + w * 64 + lane;                                                 \
      int key = gi >> 4, gd = gi & 15;                                                  \
      int gsrc = gd ^ (key & 7);                                                        \
      gload16(&k[(size_t)(kb_ + key) * (NKV * HD) + kvh * HD + gsrc * 8],               \
              &Ks[BUF][(i * 256 + w * 64) * 8]);                                        \
    }                                                                                   \
    _Pragma("unroll") for (int i = 0; i < 4; i++) {                                     \
      int gi = i * 256 + w * 64 + lane;                                                 \
      int d = gi >> 3, gc = gi & 7;                                                     \
      int gsrc = gc ^ (d & 7);                                                          \
      gload16(&vT[(size_t)(kvh * HD + d) * SEQ + kb_ + gsrc * 8],                       \
              &Vs[BUF][(i * 256 + w * 64) * 8]);                                        \
    }                                                                                   \
  } while (0)

  STAGE(0, 0);
  __syncthreads();  // vmcnt(0) drain: tile 0 resident

  for (int t = 0; t < ntiles; t++) {
    const int cur = t & 1;
    const int kb = t * 64;
    if (t + 1 < ntiles) STAGE(cur ^ 1, t + 1);  // prefetch next tile (lands at barrier)

    const bool tail = (kb + 64 > q0);
#pragma unroll
    for (int m = 0; m < 2; m++) {
      const int rbase = q0 + w * 32 + m * 16;
      if (kb > rbase + 15) continue;  // fragment fully masked

      // ---- QK^T: S[16 rows][64 keys] ----
      f32x4 sfr[4];
      __builtin_amdgcn_s_setprio(1);
#pragma unroll
      for (int kb4 = 0; kb4 < 4; kb4++) {
        f32x4 acc = (f32x4){0.f, 0.f, 0.f, 0.f};
        const int key = kb4 * 16 + r16;
#pragma unroll
        for (int ks = 0; ks < 4; ks++) {
          short8 kf = *(const short8*)&Ks[cur][key * 128 + (((4 * ks + g) ^ (key & 7)) * 8)];
          acc = __builtin_amdgcn_mfma_f32_16x16x32_bf16(qf[m][ks], kf, acc, 0, 0, 0);
        }
        sfr[kb4] = acc;
      }
      __builtin_amdgcn_s_setprio(0);
#pragma unroll
      for (int kb4 = 0; kb4 < 4; kb4++)
#pragma unroll
        for (int r = 0; r < 4; r++) {
          float s = sfr[kb4][r] * scale;
          if (tail && (kb + kb4 * 16 + r16 > rbase + 4 * g + r)) s = -1e30f;
          sfr[kb4][r] = s;
        }
      // ---- online softmax ----
      float pmax[4], resc[4];
#pragma unroll
      for (int r = 0; r < 4; r++) {
        float x = fmaxf(fmaxf(sfr[0][r], sfr[1][r]), fmaxf(sfr[2][r], sfr[3][r]));
        x = fmaxf(x, __shfl_xor(x, 1));
        x = fmaxf(x, __shfl_xor(x, 2));
        x = fmaxf(x, __shfl_xor(x, 4));
        x = fmaxf(x, __shfl_xor(x, 8));
        pmax[r] = x;
      }
#pragma unroll
      for (int r = 0; r < 4; r++) {
        float nm = fmaxf(mrow[m][r], pmax[r]);
        resc[r] = __expf(mrow[m][r] - nm);
        mrow[m][r] = nm;
      }
      float psum[4] = {0.f, 0.f, 0.f, 0.f};
#pragma unroll
      for (int kb4 = 0; kb4 < 4; kb4++)
#pragma unroll
        for (int r = 0; r < 4; r++) {
          float p = __expf(sfr[kb4][r] - mrow[m][r]);
          psum[r] += p;
          Ps[w][4 * g + r][kb4 * 16 + r16] = f2bf(p);
        }
#pragma unroll
      for (int r = 0; r < 4; r++) {
        float s = psum[r];
        s += __shfl_xor(s, 1); s += __shfl_xor(s, 2);
        s += __shfl_xor(s, 4); s += __shfl_xor(s, 8);
        lrow[m][r] = lrow[m][r] * resc[r] + s;
      }
#pragma unroll
      for (int d = 0; d < 8; d++)
#pragma unroll
        for (int r = 0; r < 4; r++) oa[m][d][r] *= resc[r];

      // ---- PV: O[16][128] += P[16][64] @ V[64][128] ----
      short8 pf[2];
      pf[0] = *(const short8*)&Ps[w][r16][g * 8];
      pf[1] = *(const short8*)&Ps[w][r16][32 + g * 8];
      __builtin_amdgcn_s_setprio(1);
#pragma unroll
      for (int d = 0; d < 8; d++) {
        const int dd = d * 16 + r16;
#pragma unroll
        for (int ks2 = 0; ks2 < 2; ks2++) {
          short8 vf = *(const short8*)&Vs[cur][dd * 64 + (((4 * ks2 + g) ^ (dd & 7)) * 8)];
          oa[m][d] = __builtin_amdgcn_mfma_f32_16x16x32_bf16(pf[ks2], vf, oa[m][d], 0, 0, 0);
        }
      }
      __builtin_amdgcn_s_setprio(0);
    }
    __syncthreads();  // prefetch landed + all waves done reading cur
  }
#undef STAGE
  // epilogue
#pragma unroll
  for (int m = 0; m < 2; m++)
#pragma unroll
    for (int d = 0; d < 8; d++)
#pragma unroll
      for (int r = 0; r < 4; r++) {
        int row = q0 + w * 32 + m * 16 + 4 * g + r;
        int col = h * HD + d * 16 + r16;
        out[(size_t)row * (NH * HD) + col] = f2bf(oa[m][d][r] / lrow[m][r]);
      }
}

extern "C" void kernel_launch(void* const* d_in, const int* in_sizes, int n_in,
                              void* d_out, int out_size, void* d_ws, size_t ws_size,
                              hipStream_t stream) {
  const float* x    = (const float*)d_in[0];
  const float* wq   = (const float*)d_in[1];
  const float* bq   = (const float*)d_in[2];
  const float* wk   = (const float*)d_in[3];
  const float* bk   = (const float*)d_in[4];
  const float* wv   = (const float*)d_in[5];
  const float* bv   = (const float*)d_in[6];
  const float* wo   = (const float*)d_in[7];
  const float* cosd = (const float*)d_in[8];
  const float* sind = (const float*)d_in[9];
  float* out = (float*)d_out;

  ushort_t* ws   = (ushort_t*)d_ws;
  ushort_t* wT   = ws;                              // [4608][3584] qkv^T; later wo^T
  ushort_t* xb   = wT + (size_t)NQKV * HID;         // [2048][3584] (later attn out)
  ushort_t* qb   = xb + (size_t)SEQ * HID;          // [2048][3584]
  ushort_t* kb_  = qb + (size_t)SEQ * HID;          // [2048][512]
  ushort_t* vbT  = kb_ + (size_t)SEQ * (NKV * HD);  // [512][2048]
  ushort_t* aob  = xb;                              // reuse after QKV GEMM

  // 1. cast x -> bf16
  cast_bf16_kernel<<<(SEQ * HID / 4) / 256, 256, 0, stream>>>(x, xb, SEQ * HID / 4);
  // 2. transpose-cast weights into fused [4608][3584]
  transpose_cast_kernel<<<dim3(HID / 64, HID / 64), 256, 0, stream>>>(wq, wT, HID, HID);
  transpose_cast_kernel<<<dim3((NKV * HD) / 64, HID / 64), 256, 0, stream>>>(
      wk, wT + (size_t)(NH * HD) * HID, HID, NKV * HD);
  transpose_cast_kernel<<<dim3((NKV * HD) / 64, HID / 64), 256, 0, stream>>>(
      wv, wT + (size_t)(NH * HD + NKV * HD) * HID, HID, NKV * HD);
  // 3. fused QKV projection
  gemm_mfma<<<dim3(NQKV / 128, SEQ / 128), 256, 0, stream>>>(
      xb, wT, bq, nullptr, qb, kb_, vbT, bk, bv, SEQ, NQKV, HID, 3);
  // 4. RoPE on q, k
  rope_kernel<<<dim3(SEQ, NH), 64, 0, stream>>>(qb, cosd, sind, NH);
  rope_kernel<<<dim3(SEQ, NKV), 64, 0, stream>>>(kb_, cosd, sind, NKV);
  // 5. attention
  attn_mfma<<<dim3(SEQ / 128, NH), 256, 0, stream>>>(qb, kb_, vbT, aob);
  // 6. output projection (reuse wT region for wo^T)
  transpose_cast_kernel<<<dim3(HID / 64, HID / 64), 256, 0, stream>>>(wo, wT, HID, HID);
  gemm_mfma<<<dim3(HID / 128, SEQ / 128), 256, 0, stream>>>(
      aob, wT, nullptr, out, nullptr, nullptr, nullptr, nullptr, nullptr, SEQ, HID, HID, 0);
}

// Round 5
// 441.095 us; speedup vs baseline: 18.1887x; 1.1050x over previous
//
#include <hip/hip_runtime.h>
#include <math.h>

#define SEQ 2048
#define HID 3584
#define NH 28
#define NKV 4
#define HD 128
#define GQA (NH / NKV)
#define NQKV (NH * HD + 2 * NKV * HD)  // 4608
#define NSLOT 30                       // total (qtile, chunk) pairs per head

typedef __attribute__((ext_vector_type(8))) short short8;
typedef __attribute__((ext_vector_type(4))) float f32x4;
typedef unsigned int u32;
typedef unsigned short ushort_t;

__device__ inline ushort_t f2bf(float f) {
  u32 x = __float_as_uint(f);
  return (ushort_t)((x + 0x7FFFu + ((x >> 16) & 1u)) >> 16);
}
__device__ inline float bf2f(ushort_t h) {
  return __uint_as_float(((u32)h) << 16);
}
__device__ inline void gload16(const void* g, void* l) {
  __builtin_amdgcn_global_load_lds((const u32 __attribute__((address_space(1)))*)g,
                                   (u32 __attribute__((address_space(3)))*)l, 16, 0, 0);
}

// ---------------- cast x -> bf16 ----------------
__global__ __launch_bounds__(256) void cast_bf16_kernel(const float* __restrict__ in,
                                                        ushort_t* __restrict__ out, int n4) {
  int i = blockIdx.x * blockDim.x + threadIdx.x;
  if (i >= n4) return;
  float4 v = ((const float4*)in)[i];
  ushort4 o;
  o.x = f2bf(v.x); o.y = f2bf(v.y); o.z = f2bf(v.z); o.w = f2bf(v.w);
  *(ushort4*)&out[(size_t)i * 4] = o;
}

// ---------------- transpose-cast: in [K][N] f32 -> out [N][K] bf16 ----------------
__global__ __launch_bounds__(256) void transpose_cast_kernel(const float* __restrict__ in,
                                                             ushort_t* __restrict__ out,
                                                             int K, int N) {
  __shared__ ushort_t t[64][65];
  const int bk = blockIdx.y * 64, bn = blockIdx.x * 64;
  const int tid = threadIdx.x;
#pragma unroll
  for (int i = 0; i < 4; i++) {
    int idx = i * 256 + tid;
    int r = idx >> 4, c4 = idx & 15;
    float4 v = *(const float4*)&in[(size_t)(bk + r) * N + bn + c4 * 4];
    t[c4 * 4 + 0][r] = f2bf(v.x);
    t[c4 * 4 + 1][r] = f2bf(v.y);
    t[c4 * 4 + 2][r] = f2bf(v.z);
    t[c4 * 4 + 3][r] = f2bf(v.w);
  }
  __syncthreads();
#pragma unroll
  for (int i = 0; i < 4; i++) {
    int idx = i * 256 + tid;
    int r = idx >> 4, c4 = idx & 15;
    ushort4 o;
    o.x = t[r][c4 * 4 + 0]; o.y = t[r][c4 * 4 + 1];
    o.z = t[r][c4 * 4 + 2]; o.w = t[r][c4 * 4 + 3];
    *(ushort4*)&out[(size_t)(bn + r) * K + bk + c4 * 4] = o;
  }
}

// ---------------- bf16 MFMA GEMM ----------------
// C[M][N] = A[M][K] @ BT[N][K]^T (+bias).
// mode 0: f32 out (Cf). mode 1: bf16 out (Cb).
// mode 3: fused QKV routing: cols [0,3584)->Cb (q), [3584,4096)->Ck (k),
//         [4096,4608)->Cv transposed (vT).
__global__ __launch_bounds__(256) void gemm_mfma(
    const ushort_t* __restrict__ A, const ushort_t* __restrict__ BT,
    const float* __restrict__ bias, float* __restrict__ Cf, ushort_t* __restrict__ Cb,
    ushort_t* __restrict__ Ck, ushort_t* __restrict__ Cv,
    const float* __restrict__ bias_k, const float* __restrict__ bias_v,
    int M, int N, int K, int mode) {
  __shared__ __align__(16) ushort_t As[2][128 * 32];
  __shared__ __align__(16) ushort_t Bs[2][128 * 32];
  const int tid = threadIdx.x;
  const int w = tid >> 6, lane = tid & 63;
  const int g = lane >> 4, r16 = lane & 15;
  const int wr = w >> 1, wc = w & 1;
  const int bm = blockIdx.y * 128, bn = blockIdx.x * 128;

  f32x4 acc[4][4];
#pragma unroll
  for (int i = 0; i < 4; i++)
#pragma unroll
    for (int j = 0; j < 4; j++) acc[i][j] = (f32x4){0.f, 0.f, 0.f, 0.f};

  const int nk = K >> 5;
#pragma unroll
  for (int i = 0; i < 2; i++) {
    int gi = i * 256 + w * 64 + lane;
    int row = gi >> 2, gc = gi & 3;
    gload16(&A[(size_t)(bm + row) * K + gc * 8], &As[0][(i * 256 + w * 64) * 8]);
    gload16(&BT[(size_t)(bn + row) * K + gc * 8], &Bs[0][(i * 256 + w * 64) * 8]);
  }
  __syncthreads();

  int buf = 0;
  for (int kt = 0; kt < nk; kt++) {
    if (kt + 1 < nk) {
      const int k0 = (kt + 1) << 5;
#pragma unroll
      for (int i = 0; i < 2; i++) {
        int gi = i * 256 + w * 64 + lane;
        int row = gi >> 2, gc = gi & 3;
        gload16(&A[(size_t)(bm + row) * K + k0 + gc * 8], &As[buf ^ 1][(i * 256 + w * 64) * 8]);
        gload16(&BT[(size_t)(bn + row) * K + k0 + gc * 8], &Bs[buf ^ 1][(i * 256 + w * 64) * 8]);
      }
    }
    short8 af[4], bfr[4];
#pragma unroll
    for (int mi = 0; mi < 4; mi++)
      af[mi] = *(const short8*)&As[buf][((wr * 64 + mi * 16 + r16) * 4 + g) * 8];
#pragma unroll
    for (int ni = 0; ni < 4; ni++)
      bfr[ni] = *(const short8*)&Bs[buf][((wc * 64 + ni * 16 + r16) * 4 + g) * 8];
    __builtin_amdgcn_s_setprio(1);
#pragma unroll
    for (int mi = 0; mi < 4; mi++)
#pragma unroll
      for (int ni = 0; ni < 4; ni++)
        acc[mi][ni] = __builtin_amdgcn_mfma_f32_16x16x32_bf16(af[mi], bfr[ni], acc[mi][ni], 0, 0, 0);
    __builtin_amdgcn_s_setprio(0);
    __syncthreads();
    buf ^= 1;
  }

  if (mode == 3) {
#pragma unroll
    for (int mi = 0; mi < 4; mi++)
#pragma unroll
      for (int ni = 0; ni < 4; ni++)
#pragma unroll
        for (int r = 0; r < 4; r++) {
          int row = bm + wr * 64 + mi * 16 + 4 * g + r;
          int col = bn + wc * 64 + ni * 16 + r16;
          float v = acc[mi][ni][r];
          if (bn < NH * HD) {
            Cb[(size_t)row * (NH * HD) + col] = f2bf(v + bias[col]);
          } else if (bn < NH * HD + NKV * HD) {
            int c = col - NH * HD;
            Ck[(size_t)row * (NKV * HD) + c] = f2bf(v + bias_k[c]);
          } else {
            int c = col - (NH * HD + NKV * HD);
            Cv[(size_t)c * M + row] = f2bf(v + bias_v[c]);
          }
        }
    return;
  }
#pragma unroll
  for (int mi = 0; mi < 4; mi++)
#pragma unroll
    for (int ni = 0; ni < 4; ni++)
#pragma unroll
      for (int r = 0; r < 4; r++) {
        int row = bm + wr * 64 + mi * 16 + 4 * g + r;
        int col = bn + wc * 64 + ni * 16 + r16;
        float v = acc[mi][ni][r];
        if (bias) v += bias[col];
        if (mode == 0) Cf[(size_t)row * N + col] = v;
        else Cb[(size_t)row * N + col] = f2bf(v);
      }
}

// ---------------- RoPE in-place on bf16 [S][nheads][128] ----------------
__global__ void rope_kernel(ushort_t* __restrict__ buf, const float* __restrict__ cosd,
                            const float* __restrict__ sind, int nheads) {
  const int s = blockIdx.x, h = blockIdx.y, d = threadIdx.x;  // d: 0..63
  const float c = cosd[s * 64 + d], sn = sind[s * 64 + d];
  ushort_t* p = buf + ((size_t)s * nheads + h) * HD;
  float x1 = bf2f(p[d]), x2 = bf2f(p[d + 64]);
  p[d] = f2bf(x1 * c - x2 * sn);
  p[d + 64] = f2bf(x1 * sn + x2 * c);
}

// ---------------- split-K MFMA causal GQA flash attention ----------------
// Each block: 128 q-rows x one 768-key chunk (<=12 tiles of 64 keys).
// Writes UNNORMALIZED partials: Opart bf16 [NH][NSLOT][128 rows][128 d],
// Mpart/Lpart f32 [NH][NSLOT][128 rows].
// Slot map (per head): qt 0..5 -> 1 chunk, 6..11 -> 2, 12..15 -> 3 (total 30).
__global__ __launch_bounds__(256) void attn_split(
    const ushort_t* __restrict__ q, const ushort_t* __restrict__ k,
    const ushort_t* __restrict__ vT, ushort_t* __restrict__ Opart,
    float* __restrict__ Mpart, float* __restrict__ Lpart) {
  const int b = (NSLOT - 1) - blockIdx.x;  // longer chunks dispatch first
  int qt, c;
  if (b < 6) { qt = b; c = 0; }
  else if (b < 18) { qt = 6 + (b - 6) / 2; c = (b - 6) & 1; }
  else { qt = 12 + (b - 18) / 3; c = (b - 18) % 3; }
  const int h = blockIdx.y, kvh = h / GQA;
  const int q0 = qt * 128;
  const int tstart = c * 12;
  const int tend = min(tstart + 12, 2 * qt + 2);
  const int tid = threadIdx.x, w = tid >> 6, lane = tid & 63;
  const int g = lane >> 4, r16 = lane & 15;

  __shared__ __align__(16) ushort_t Ks[2][64 * 128];  // [key][d], granule-swizzled by key&7
  __shared__ __align__(16) ushort_t Vs[2][128 * 64];  // [d][key], granule-swizzled by d&7
  __shared__ __align__(16) ushort_t Ps[4][16][72];    // per-wave P (16 rows, per-m reuse)

  short8 qf[2][4];
#pragma unroll
  for (int m = 0; m < 2; m++) {
    const ushort_t* qp = q + (size_t)(q0 + w * 32 + m * 16 + r16) * (NH * HD) + h * HD;
#pragma unroll
    for (int f = 0; f < 4; f++) qf[m][f] = *(const short8*)(qp + f * 32 + g * 8);
  }
  float mrow[2][4], lrow[2][4];
#pragma unroll
  for (int m = 0; m < 2; m++)
#pragma unroll
    for (int r = 0; r < 4; r++) { mrow[m][r] = -1e30f; lrow[m][r] = 0.f; }
  f32x4 oa[2][8];
#pragma unroll
  for (int m = 0; m < 2; m++)
#pragma unroll
    for (int d = 0; d < 8; d++) oa[m][d] = (f32x4){0.f, 0.f, 0.f, 0.f};

  const float scale = 0.08838834764831845f;

#define STAGE(BUF, T)                                                                   \
  do {                                                                                  \
    const int kb_ = (T) * 64;                                                           \
    _Pragma("unroll") for (int i = 0; i < 4; i++) {                                     \
      int gi = i * 256 + w * 64 + lane;                                                 \
      int key = gi >> 4, gd = gi & 15;                                                  \
      int gsrc = gd ^ (key & 7);                                                        \
      gload16(&k[(size_t)(kb_ + key) * (NKV * HD) + kvh * HD + gsrc * 8],               \
              &Ks[BUF][(i * 256 + w * 64) * 8]);                                        \
    }                                                                                   \
    _Pragma("unroll") for (int i = 0; i < 4; i++) {                                     \
      int gi = i * 256 + w * 64 + lane;                                                 \
      int d = gi >> 3, gc = gi & 7;                                                     \
      int gsrc = gc ^ (d & 7);                                                          \
      gload16(&vT[(size_t)(kvh * HD + d) * SEQ + kb_ + gsrc * 8],                       \
              &Vs[BUF][(i * 256 + w * 64) * 8]);                                        \
    }                                                                                   \
  } while (0)

  STAGE(0, tstart);
  __syncthreads();  // vmcnt(0) drain: first tile resident

  for (int t = tstart; t < tend; t++) {
    const int cur = (t - tstart) & 1;
    const int kb = t * 64;
    if (t + 1 < tend) STAGE(cur ^ 1, t + 1);  // prefetch next tile (lands at barrier)

    const bool tail = (kb + 64 > q0);
    const int rb0 = q0 + w * 32;          // m=0 fragment rows rb0..rb0+15
    const bool act0 = (kb <= rb0 + 15);
    const bool act1 = (kb <= rb0 + 31);   // m=1 rows rb0+16..rb0+31

    // ---- fused QK^T for both fragments: shared K-fragment loads ----
    f32x4 sfr[2][4];
    __builtin_amdgcn_s_setprio(1);
#pragma unroll
    for (int kb4 = 0; kb4 < 4; kb4++) {
      f32x4 a0 = (f32x4){0.f, 0.f, 0.f, 0.f};
      f32x4 a1 = (f32x4){0.f, 0.f, 0.f, 0.f};
      const int key = kb4 * 16 + r16;
#pragma unroll
      for (int ks = 0; ks < 4; ks++) {
        short8 kf = *(const short8*)&Ks[cur][key * 128 + (((4 * ks + g) ^ (key & 7)) * 8)];
        if (act0) a0 = __builtin_amdgcn_mfma_f32_16x16x32_bf16(qf[0][ks], kf, a0, 0, 0, 0);
        if (act1) a1 = __builtin_amdgcn_mfma_f32_16x16x32_bf16(qf[1][ks], kf, a1, 0, 0, 0);
      }
      sfr[0][kb4] = a0; sfr[1][kb4] = a1;
    }
    __builtin_amdgcn_s_setprio(0);

#pragma unroll
    for (int m = 0; m < 2; m++) {
      if (m == 0 ? !act0 : !act1) continue;
      const int rbase = rb0 + m * 16;
#pragma unroll
      for (int kb4 = 0; kb4 < 4; kb4++)
#pragma unroll
        for (int r = 0; r < 4; r++) {
          float s = sfr[m][kb4][r] * scale;
          if (tail && (kb + kb4 * 16 + r16 > rbase + 4 * g + r)) s = -1e30f;
          sfr[m][kb4][r] = s;
        }
      // ---- online softmax ----
      float pmax[4], resc[4];
#pragma unroll
      for (int r = 0; r < 4; r++) {
        float x = fmaxf(fmaxf(sfr[m][0][r], sfr[m][1][r]), fmaxf(sfr[m][2][r], sfr[m][3][r]));
        x = fmaxf(x, __shfl_xor(x, 1));
        x = fmaxf(x, __shfl_xor(x, 2));
        x = fmaxf(x, __shfl_xor(x, 4));
        x = fmaxf(x, __shfl_xor(x, 8));
        pmax[r] = x;
      }
#pragma unroll
      for (int r = 0; r < 4; r++) {
        float nm = fmaxf(mrow[m][r], pmax[r]);
        resc[r] = __expf(mrow[m][r] - nm);
        mrow[m][r] = nm;
      }
      float psum[4] = {0.f, 0.f, 0.f, 0.f};
#pragma unroll
      for (int kb4 = 0; kb4 < 4; kb4++)
#pragma unroll
        for (int r = 0; r < 4; r++) {
          float p = __expf(sfr[m][kb4][r] - mrow[m][r]);
          psum[r] += p;
          Ps[w][4 * g + r][kb4 * 16 + r16] = f2bf(p);
        }
#pragma unroll
      for (int r = 0; r < 4; r++) {
        float s = psum[r];
        s += __shfl_xor(s, 1); s += __shfl_xor(s, 2);
        s += __shfl_xor(s, 4); s += __shfl_xor(s, 8);
        lrow[m][r] = lrow[m][r] * resc[r] + s;
      }
#pragma unroll
      for (int d = 0; d < 8; d++)
#pragma unroll
        for (int r = 0; r < 4; r++) oa[m][d][r] *= resc[r];

      // ---- PV: O[16][128] += P[16][64] @ V[64][128] ----
      short8 pf[2];
      pf[0] = *(const short8*)&Ps[w][r16][g * 8];
      pf[1] = *(const short8*)&Ps[w][r16][32 + g * 8];
      __builtin_amdgcn_s_setprio(1);
#pragma unroll
      for (int d = 0; d < 8; d++) {
        const int dd = d * 16 + r16;
#pragma unroll
        for (int ks2 = 0; ks2 < 2; ks2++) {
          short8 vf = *(const short8*)&Vs[cur][dd * 64 + (((4 * ks2 + g) ^ (dd & 7)) * 8)];
          oa[m][d] = __builtin_amdgcn_mfma_f32_16x16x32_bf16(pf[ks2], vf, oa[m][d], 0, 0, 0);
        }
      }
      __builtin_amdgcn_s_setprio(0);
    }
    __syncthreads();  // prefetch landed + all waves done reading cur
  }
#undef STAGE
  // epilogue: write unnormalized partials
  const size_t slot = (size_t)h * NSLOT + b;
#pragma unroll
  for (int m = 0; m < 2; m++) {
#pragma unroll
    for (int d = 0; d < 8; d++)
#pragma unroll
      for (int r = 0; r < 4; r++) {
        int lr = w * 32 + m * 16 + 4 * g + r;
        int col = d * 16 + r16;
        Opart[(slot * 128 + lr) * 128 + col] = f2bf(oa[m][d][r]);
      }
    if (r16 == 0) {
#pragma unroll
      for (int r = 0; r < 4; r++) {
        int lr = w * 32 + m * 16 + 4 * g + r;
        Mpart[slot * 128 + lr] = mrow[m][r];
        Lpart[slot * 128 + lr] = lrow[m][r];
      }
    }
  }
}

// ---------------- combine split-K partials ----------------
__global__ __launch_bounds__(128) void attn_reduce(
    const ushort_t* __restrict__ Opart, const float* __restrict__ Mpart,
    const float* __restrict__ Lpart, ushort_t* __restrict__ out) {
  const int s = blockIdx.x, h = blockIdx.y, d = threadIdx.x;
  const int qt = s >> 7;
  const int C = (qt + 6) / 6;  // 1, 2 or 3 chunks
  const int b0 = qt < 6 ? qt : (qt < 12 ? 6 + 2 * (qt - 6) : 18 + 3 * (qt - 12));
  const int lr = s & 127;
  const size_t base = ((size_t)h * NSLOT + b0) * 128 + lr;
  float M = -1e30f;
  for (int c = 0; c < C; c++) M = fmaxf(M, Mpart[base + c * 128]);
  float L = 0.f, O = 0.f;
  for (int c = 0; c < C; c++) {
    float wgt = __expf(Mpart[base + c * 128] - M);
    L += wgt * Lpart[base + c * 128];
    O += wgt * bf2f(Opart[(base + c * 128) * 128 + d]);
  }
  out[(size_t)s * (NH * HD) + h * HD + d] = f2bf(O / L);
}

extern "C" void kernel_launch(void* const* d_in, const int* in_sizes, int n_in,
                              void* d_out, int out_size, void* d_ws, size_t ws_size,
                              hipStream_t stream) {
  const float* x    = (const float*)d_in[0];
  const float* wq   = (const float*)d_in[1];
  const float* bq   = (const float*)d_in[2];
  const float* wk   = (const float*)d_in[3];
  const float* bk   = (const float*)d_in[4];
  const float* wv   = (const float*)d_in[5];
  const float* bv   = (const float*)d_in[6];
  const float* wo   = (const float*)d_in[7];
  const float* cosd = (const float*)d_in[8];
  const float* sind = (const float*)d_in[9];
  float* out = (float*)d_out;

  ushort_t* ws   = (ushort_t*)d_ws;
  ushort_t* wT   = ws;                              // [4608][3584] qkv^T; later partials; later wo^T
  ushort_t* xb   = wT + (size_t)NQKV * HID;         // [2048][3584] (later attn out)
  ushort_t* qb   = xb + (size_t)SEQ * HID;          // [2048][3584]
  ushort_t* kb_  = qb + (size_t)SEQ * HID;          // [2048][512]
  ushort_t* vbT  = kb_ + (size_t)SEQ * (NKV * HD);  // [512][2048]
  ushort_t* aob  = xb;                              // reuse after QKV GEMM

  // split-K partials overlay the (dead after QKV GEMM) wT region: 27.5MB + 0.86MB <= 33MB
  ushort_t* Opart = wT;                                             // [28][30][128][128] bf16
  float* Mpart = (float*)(wT + (size_t)NH * NSLOT * 128 * 128);     // [28][30][128]
  float* Lpart = Mpart + (size_t)NH * NSLOT * 128;                  // [28][30][128]

  // 1. cast x -> bf16
  cast_bf16_kernel<<<(SEQ * HID / 4) / 256, 256, 0, stream>>>(x, xb, SEQ * HID / 4);
  // 2. transpose-cast weights into fused [4608][3584]
  transpose_cast_kernel<<<dim3(HID / 64, HID / 64), 256, 0, stream>>>(wq, wT, HID, HID);
  transpose_cast_kernel<<<dim3((NKV * HD) / 64, HID / 64), 256, 0, stream>>>(
      wk, wT + (size_t)(NH * HD) * HID, HID, NKV * HD);
  transpose_cast_kernel<<<dim3((NKV * HD) / 64, HID / 64), 256, 0, stream>>>(
      wv, wT + (size_t)(NH * HD + NKV * HD) * HID, HID, NKV * HD);
  // 3. fused QKV projection
  gemm_mfma<<<dim3(NQKV / 128, SEQ / 128), 256, 0, stream>>>(
      xb, wT, bq, nullptr, qb, kb_, vbT, bk, bv, SEQ, NQKV, HID, 3);
  // 4. RoPE on q, k
  rope_kernel<<<dim3(SEQ, NH), 64, 0, stream>>>(qb, cosd, sind, NH);
  rope_kernel<<<dim3(SEQ, NKV), 64, 0, stream>>>(kb_, cosd, sind, NKV);
  // 5. split-K attention + reduce
  attn_split<<<dim3(NSLOT, NH), 256, 0, stream>>>(qb, kb_, vbT, Opart, Mpart, Lpart);
  attn_reduce<<<dim3(SEQ, NH), 128, 0, stream>>>(Opart, Mpart, Lpart, aob);
  // 6. output projection (reuse wT region for wo^T; partials dead after reduce)
  transpose_cast_kernel<<<dim3(HID / 64, HID / 64), 256, 0, stream>>>(wo, wT, HID, HID);
  gemm_mfma<<<dim3(HID / 128, SEQ / 128), 256, 0, stream>>>(
      aob, wT, nullptr, out, nullptr, nullptr, nullptr, nullptr, nullptr, SEQ, HID, HID, 0);
}

// Round 6
// 437.010 us; speedup vs baseline: 18.3587x; 1.0093x over previous
//
#include <hip/hip_runtime.h>
#include <math.h>

#define SEQ 2048
#define HID 3584
#define NH 28
#define NKV 4
#define HD 128
#define GQA (NH / NKV)
#define NQKV (NH * HD + 2 * NKV * HD)  // 4608
#define NSLOT 60                       // (qtile, chunk) slots per head, QBLK=64, CHUNK=12 tiles
#define KS2 0.12752997f                // (1/sqrt(128)) * log2(e)
#define DTHR 90.50967f                 // 8 / (1/sqrt(128)) : defer-max threshold (raw domain)

typedef __attribute__((ext_vector_type(8))) short short8;
typedef __attribute__((ext_vector_type(4))) float f32x4;
typedef unsigned int u32;
typedef unsigned short ushort_t;

__device__ inline ushort_t f2bf(float f) {
  u32 x = __float_as_uint(f);
  return (ushort_t)((x + 0x7FFFu + ((x >> 16) & 1u)) >> 16);
}
__device__ inline float bf2f(ushort_t h) {
  return __uint_as_float(((u32)h) << 16);
}
__device__ inline void gload16(const void* g, void* l) {
  __builtin_amdgcn_global_load_lds((const u32 __attribute__((address_space(1)))*)g,
                                   (u32 __attribute__((address_space(3)))*)l, 16, 0, 0);
}

// ---------------- cast x -> bf16 ----------------
__global__ __launch_bounds__(256) void cast_bf16_kernel(const float* __restrict__ in,
                                                        ushort_t* __restrict__ out, int n4) {
  int i = blockIdx.x * blockDim.x + threadIdx.x;
  if (i >= n4) return;
  float4 v = ((const float4*)in)[i];
  ushort4 o;
  o.x = f2bf(v.x); o.y = f2bf(v.y); o.z = f2bf(v.z); o.w = f2bf(v.w);
  *(ushort4*)&out[(size_t)i * 4] = o;
}

// ---------------- transpose-cast: in [K][N] f32 -> out [N][K] bf16 ----------------
__global__ __launch_bounds__(256) void transpose_cast_kernel(const float* __restrict__ in,
                                                             ushort_t* __restrict__ out,
                                                             int K, int N) {
  __shared__ ushort_t t[64][65];
  const int bk = blockIdx.y * 64, bn = blockIdx.x * 64;
  const int tid = threadIdx.x;
#pragma unroll
  for (int i = 0; i < 4; i++) {
    int idx = i * 256 + tid;
    int r = idx >> 4, c4 = idx & 15;
    float4 v = *(const float4*)&in[(size_t)(bk + r) * N + bn + c4 * 4];
    t[c4 * 4 + 0][r] = f2bf(v.x);
    t[c4 * 4 + 1][r] = f2bf(v.y);
    t[c4 * 4 + 2][r] = f2bf(v.z);
    t[c4 * 4 + 3][r] = f2bf(v.w);
  }
  __syncthreads();
#pragma unroll
  for (int i = 0; i < 4; i++) {
    int idx = i * 256 + tid;
    int r = idx >> 4, c4 = idx & 15;
    ushort4 o;
    o.x = t[r][c4 * 4 + 0]; o.y = t[r][c4 * 4 + 1];
    o.z = t[r][c4 * 4 + 2]; o.w = t[r][c4 * 4 + 3];
    *(ushort4*)&out[(size_t)(bn + r) * K + bk + c4 * 4] = o;
  }
}

// ---------------- bf16 MFMA GEMM ----------------
// C[M][N] = A[M][K] @ BT[N][K]^T (+bias).
// mode 0: f32 out (Cf). mode 1: bf16 out (Cb).
// mode 3: fused QKV routing: cols [0,3584)->Cb (q), [3584,4096)->Ck (k),
//         [4096,4608)->Cv transposed (vT).
__global__ __launch_bounds__(256) void gemm_mfma(
    const ushort_t* __restrict__ A, const ushort_t* __restrict__ BT,
    const float* __restrict__ bias, float* __restrict__ Cf, ushort_t* __restrict__ Cb,
    ushort_t* __restrict__ Ck, ushort_t* __restrict__ Cv,
    const float* __restrict__ bias_k, const float* __restrict__ bias_v,
    int M, int N, int K, int mode) {
  __shared__ __align__(16) ushort_t As[2][128 * 32];
  __shared__ __align__(16) ushort_t Bs[2][128 * 32];
  const int tid = threadIdx.x;
  const int w = tid >> 6, lane = tid & 63;
  const int g = lane >> 4, r16 = lane & 15;
  const int wr = w >> 1, wc = w & 1;
  const int bm = blockIdx.y * 128, bn = blockIdx.x * 128;

  f32x4 acc[4][4];
#pragma unroll
  for (int i = 0; i < 4; i++)
#pragma unroll
    for (int j = 0; j < 4; j++) acc[i][j] = (f32x4){0.f, 0.f, 0.f, 0.f};

  const int nk = K >> 5;
#pragma unroll
  for (int i = 0; i < 2; i++) {
    int gi = i * 256 + w * 64 + lane;
    int row = gi >> 2, gc = gi & 3;
    gload16(&A[(size_t)(bm + row) * K + gc * 8], &As[0][(i * 256 + w * 64) * 8]);
    gload16(&BT[(size_t)(bn + row) * K + gc * 8], &Bs[0][(i * 256 + w * 64) * 8]);
  }
  __syncthreads();

  int buf = 0;
  for (int kt = 0; kt < nk; kt++) {
    if (kt + 1 < nk) {
      const int k0 = (kt + 1) << 5;
#pragma unroll
      for (int i = 0; i < 2; i++) {
        int gi = i * 256 + w * 64 + lane;
        int row = gi >> 2, gc = gi & 3;
        gload16(&A[(size_t)(bm + row) * K + k0 + gc * 8], &As[buf ^ 1][(i * 256 + w * 64) * 8]);
        gload16(&BT[(size_t)(bn + row) * K + k0 + gc * 8], &Bs[buf ^ 1][(i * 256 + w * 64) * 8]);
      }
    }
    short8 af[4], bfr[4];
#pragma unroll
    for (int mi = 0; mi < 4; mi++)
      af[mi] = *(const short8*)&As[buf][((wr * 64 + mi * 16 + r16) * 4 + g) * 8];
#pragma unroll
    for (int ni = 0; ni < 4; ni++)
      bfr[ni] = *(const short8*)&Bs[buf][((wc * 64 + ni * 16 + r16) * 4 + g) * 8];
    __builtin_amdgcn_s_setprio(1);
#pragma unroll
    for (int mi = 0; mi < 4; mi++)
#pragma unroll
      for (int ni = 0; ni < 4; ni++)
        acc[mi][ni] = __builtin_amdgcn_mfma_f32_16x16x32_bf16(af[mi], bfr[ni], acc[mi][ni], 0, 0, 0);
    __builtin_amdgcn_s_setprio(0);
    __syncthreads();
    buf ^= 1;
  }

  if (mode == 3) {
#pragma unroll
    for (int mi = 0; mi < 4; mi++)
#pragma unroll
      for (int ni = 0; ni < 4; ni++)
#pragma unroll
        for (int r = 0; r < 4; r++) {
          int row = bm + wr * 64 + mi * 16 + 4 * g + r;
          int col = bn + wc * 64 + ni * 16 + r16;
          float v = acc[mi][ni][r];
          if (bn < NH * HD) {
            Cb[(size_t)row * (NH * HD) + col] = f2bf(v + bias[col]);
          } else if (bn < NH * HD + NKV * HD) {
            int c = col - NH * HD;
            Ck[(size_t)row * (NKV * HD) + c] = f2bf(v + bias_k[c]);
          } else {
            int c = col - (NH * HD + NKV * HD);
            Cv[(size_t)c * M + row] = f2bf(v + bias_v[c]);
          }
        }
    return;
  }
#pragma unroll
  for (int mi = 0; mi < 4; mi++)
#pragma unroll
    for (int ni = 0; ni < 4; ni++)
#pragma unroll
      for (int r = 0; r < 4; r++) {
        int row = bm + wr * 64 + mi * 16 + 4 * g + r;
        int col = bn + wc * 64 + ni * 16 + r16;
        float v = acc[mi][ni][r];
        if (bias) v += bias[col];
        if (mode == 0) Cf[(size_t)row * N + col] = v;
        else Cb[(size_t)row * N + col] = f2bf(v);
      }
}

// ---------------- RoPE in-place on bf16 [S][nheads][128] ----------------
__global__ void rope_kernel(ushort_t* __restrict__ buf, const float* __restrict__ cosd,
                            const float* __restrict__ sind, int nheads) {
  const int s = blockIdx.x, h = blockIdx.y, d = threadIdx.x;  // d: 0..63
  const float c = cosd[s * 64 + d], sn = sind[s * 64 + d];
  ushort_t* p = buf + ((size_t)s * nheads + h) * HD;
  float x1 = bf2f(p[d]), x2 = bf2f(p[d + 64]);
  p[d] = f2bf(x1 * c - x2 * sn);
  p[d + 64] = f2bf(x1 * sn + x2 * c);
}

// ---------------- split-K MFMA causal GQA flash attention ----------------
// Block = 64 q-rows x one chunk of <=12 K-tiles (64 keys each).
// 4 waves x 16 rows. K staged in LDS (dbuf prefetch); V read direct from L2.
// Slots per head: qt 0..11 -> 1 chunk, 12..23 -> 2, 24..31 -> 3 (total 60).
// Partials unnormalized: Opart bf16 [NH][NSLOT][64][128], Mpart/Lpart f32 [NH][NSLOT][64].
// Scores kept in RAW dot-product domain; exp via exp2f(x*KS2).
__global__ __launch_bounds__(256) void attn_split(
    const ushort_t* __restrict__ q, const ushort_t* __restrict__ k,
    const ushort_t* __restrict__ vT, ushort_t* __restrict__ Opart,
    float* __restrict__ Mpart, float* __restrict__ Lpart) {
  const int b = (NSLOT - 1) - blockIdx.x;  // longest chunks dispatch first
  int qt, c;
  if (b < 12) { qt = b; c = 0; }
  else if (b < 36) { qt = 12 + (b - 12) / 2; c = (b - 12) & 1; }
  else { qt = 24 + (b - 36) / 3; c = (b - 36) % 3; }
  const int h = blockIdx.y, kvh = h / GQA;
  const int q0 = qt * 64;
  const int tstart = c * 12;
  const int tend = min(tstart + 12, qt + 1);
  const int tid = threadIdx.x, w = tid >> 6, lane = tid & 63;
  const int g = lane >> 4, r16 = lane & 15;

  __shared__ __align__(16) ushort_t Ks[2][64 * 128];  // [key][d], granule-swizzled by key&7
  __shared__ __align__(16) ushort_t Ps[4][16][72];    // per-wave P

  // Q fragment: rows q0 + w*16 + r16
  short8 qf[4];
  {
    const ushort_t* qp = q + (size_t)(q0 + w * 16 + r16) * (NH * HD) + h * HD;
#pragma unroll
    for (int f = 0; f < 4; f++) qf[f] = *(const short8*)(qp + f * 32 + g * 8);
  }
  float mrow[4], lrow[4];
#pragma unroll
  for (int r = 0; r < 4; r++) { mrow[r] = -1e30f; lrow[r] = 0.f; }
  f32x4 oa[8];
#pragma unroll
  for (int d = 0; d < 8; d++) oa[d] = (f32x4){0.f, 0.f, 0.f, 0.f};

  const ushort_t* vbase = vT + (size_t)kvh * HD * SEQ;

#define STAGE(BUF, T)                                                                   \
  do {                                                                                  \
    const int kb_ = (T) * 64;                                                           \
    _Pragma("unroll") for (int i = 0; i < 4; i++) {                                     \
      int gi = i * 256 + w * 64 + lane;                                                 \
      int key = gi >> 4, gd = gi & 15;                                                  \
      int gsrc = gd ^ (key & 7);                                                        \
      gload16(&k[(size_t)(kb_ + key) * (NKV * HD) + kvh * HD + gsrc * 8],               \
              &Ks[BUF][(i * 256 + w * 64) * 8]);                                        \
    }                                                                                   \
  } while (0)

  STAGE(0, tstart);
  __syncthreads();  // vmcnt(0) drain: first tile resident

  for (int t = tstart; t < tend; t++) {
    const int cur = (t - tstart) & 1;
    const int kb = t * 64;
    if (t + 1 < tend) STAGE(cur ^ 1, t + 1);  // prefetch next K tile

    // ---- QK^T: S[16 rows][64 keys] (raw scores) ----
    f32x4 sfr[4];
    __builtin_amdgcn_s_setprio(1);
#pragma unroll
    for (int kb4 = 0; kb4 < 4; kb4++) {
      f32x4 acc = (f32x4){0.f, 0.f, 0.f, 0.f};
      const int key = kb4 * 16 + r16;
#pragma unroll
      for (int ks = 0; ks < 4; ks++) {
        short8 kf = *(const short8*)&Ks[cur][key * 128 + (((4 * ks + g) ^ (key & 7)) * 8)];
        acc = __builtin_amdgcn_mfma_f32_16x16x32_bf16(qf[ks], kf, acc, 0, 0, 0);
      }
      sfr[kb4] = acc;
    }
    __builtin_amdgcn_s_setprio(0);

    // causal mask: only final tile (t == qt) is partial
    if (t == qt) {
#pragma unroll
      for (int kb4 = 0; kb4 < 4; kb4++)
#pragma unroll
        for (int r = 0; r < 4; r++)
          if (kb4 * 16 + r16 > w * 16 + 4 * g + r) sfr[kb4][r] = -1e30f;
    }

    // ---- online softmax (raw domain, defer-max) ----
    float pmax[4];
#pragma unroll
    for (int r = 0; r < 4; r++) {
      float x = fmaxf(fmaxf(sfr[0][r], sfr[1][r]), fmaxf(sfr[2][r], sfr[3][r]));
      x = fmaxf(x, __shfl_xor(x, 1));
      x = fmaxf(x, __shfl_xor(x, 2));
      x = fmaxf(x, __shfl_xor(x, 4));
      x = fmaxf(x, __shfl_xor(x, 8));
      pmax[r] = x;
    }
    bool ok = true;
#pragma unroll
    for (int r = 0; r < 4; r++) ok &= (pmax[r] <= mrow[r] + DTHR);
    if (!__all(ok)) {
#pragma unroll
      for (int r = 0; r < 4; r++) {
        float nm = fmaxf(mrow[r], pmax[r]);
        float resc = exp2f((mrow[r] - nm) * KS2);
        mrow[r] = nm;
        lrow[r] *= resc;
#pragma unroll
        for (int d = 0; d < 8; d++) oa[d][r] *= resc;
      }
    }
    float psum[4] = {0.f, 0.f, 0.f, 0.f};
#pragma unroll
    for (int kb4 = 0; kb4 < 4; kb4++)
#pragma unroll
      for (int r = 0; r < 4; r++) {
        float p = exp2f((sfr[kb4][r] - mrow[r]) * KS2);
        psum[r] += p;
        Ps[w][4 * g + r][kb4 * 16 + r16] = f2bf(p);
      }
#pragma unroll
    for (int r = 0; r < 4; r++) {
      float s = psum[r];
      s += __shfl_xor(s, 1); s += __shfl_xor(s, 2);
      s += __shfl_xor(s, 4); s += __shfl_xor(s, 8);
      lrow[r] += s;
    }

    // ---- PV: O[16][128] += P[16][64] @ V[64][128], V direct from L2 ----
    short8 pf[2];
    pf[0] = *(const short8*)&Ps[w][r16][g * 8];
    pf[1] = *(const short8*)&Ps[w][r16][32 + g * 8];
#pragma unroll
    for (int d = 0; d < 8; d++) {
      const int dd = d * 16 + r16;
      const ushort_t* vrow = vbase + (size_t)dd * SEQ + kb;
      short8 vf0 = *(const short8*)(vrow + g * 8);
      short8 vf1 = *(const short8*)(vrow + 32 + g * 8);
      oa[d] = __builtin_amdgcn_mfma_f32_16x16x32_bf16(pf[0], vf0, oa[d], 0, 0, 0);
      oa[d] = __builtin_amdgcn_mfma_f32_16x16x32_bf16(pf[1], vf1, oa[d], 0, 0, 0);
    }
    __syncthreads();  // K prefetch landed + all waves done with Ks[cur]
  }
#undef STAGE

  // epilogue: write unnormalized partials
  const size_t slot = (size_t)h * NSLOT + b;
#pragma unroll
  for (int d = 0; d < 8; d++)
#pragma unroll
    for (int r = 0; r < 4; r++) {
      int lr = w * 16 + 4 * g + r;
      Opart[(slot * 64 + lr) * 128 + d * 16 + r16] = f2bf(oa[d][r]);
    }
  if (r16 == 0) {
#pragma unroll
    for (int r = 0; r < 4; r++) {
      int lr = w * 16 + 4 * g + r;
      Mpart[slot * 64 + lr] = mrow[r];
      Lpart[slot * 64 + lr] = lrow[r];
    }
  }
}

// ---------------- combine split-K partials ----------------
__global__ __launch_bounds__(128) void attn_reduce(
    const ushort_t* __restrict__ Opart, const float* __restrict__ Mpart,
    const float* __restrict__ Lpart, ushort_t* __restrict__ out) {
  const int s = blockIdx.x, h = blockIdx.y, d = threadIdx.x;
  const int qt = s >> 6;
  int b0, C;
  if (qt < 12) { b0 = qt; C = 1; }
  else if (qt < 24) { b0 = 12 + 2 * (qt - 12); C = 2; }
  else { b0 = 36 + 3 * (qt - 24); C = 3; }
  const int lr = s & 63;
  const size_t base = ((size_t)h * NSLOT + b0) * 64 + lr;
  float M = -1e30f;
  for (int c = 0; c < C; c++) M = fmaxf(M, Mpart[base + c * 64]);
  float L = 0.f, O = 0.f;
  for (int c = 0; c < C; c++) {
    float wgt = exp2f((Mpart[base + c * 64] - M) * KS2);
    L += wgt * Lpart[base + c * 64];
    O += wgt * bf2f(Opart[(base + c * 64) * 128 + d]);
  }
  out[(size_t)s * (NH * HD) + h * HD + d] = f2bf(O / L);
}

extern "C" void kernel_launch(void* const* d_in, const int* in_sizes, int n_in,
                              void* d_out, int out_size, void* d_ws, size_t ws_size,
                              hipStream_t stream) {
  const float* x    = (const float*)d_in[0];
  const float* wq   = (const float*)d_in[1];
  const float* bq   = (const float*)d_in[2];
  const float* wk   = (const float*)d_in[3];
  const float* bk   = (const float*)d_in[4];
  const float* wv   = (const float*)d_in[5];
  const float* bv   = (const float*)d_in[6];
  const float* wo   = (const float*)d_in[7];
  const float* cosd = (const float*)d_in[8];
  const float* sind = (const float*)d_in[9];
  float* out = (float*)d_out;

  ushort_t* ws   = (ushort_t*)d_ws;
  ushort_t* wT   = ws;                              // [4608][3584] qkv^T; later partials; later wo^T
  ushort_t* xb   = wT + (size_t)NQKV * HID;         // [2048][3584] (later attn out)
  ushort_t* qb   = xb + (size_t)SEQ * HID;          // [2048][3584]
  ushort_t* kb_  = qb + (size_t)SEQ * HID;          // [2048][512]
  ushort_t* vbT  = kb_ + (size_t)SEQ * (NKV * HD);  // [512][2048]
  ushort_t* aob  = xb;                              // reuse after QKV GEMM

  // split-K partials overlay the (dead after QKV GEMM) wT region:
  // 28*60*64*128*2B = 27.5MB + 2*28*60*64*4B = 0.86MB <= 33MB
  ushort_t* Opart = wT;                                            // [28][60][64][128] bf16
  float* Mpart = (float*)(wT + (size_t)NH * NSLOT * 64 * 128);     // [28][60][64]
  float* Lpart = Mpart + (size_t)NH * NSLOT * 64;                  // [28][60][64]

  // 1. cast x -> bf16
  cast_bf16_kernel<<<(SEQ * HID / 4) / 256, 256, 0, stream>>>(x, xb, SEQ * HID / 4);
  // 2. transpose-cast weights into fused [4608][3584]
  transpose_cast_kernel<<<dim3(HID / 64, HID / 64), 256, 0, stream>>>(wq, wT, HID, HID);
  transpose_cast_kernel<<<dim3((NKV * HD) / 64, HID / 64), 256, 0, stream>>>(
      wk, wT + (size_t)(NH * HD) * HID, HID, NKV * HD);
  transpose_cast_kernel<<<dim3((NKV * HD) / 64, HID / 64), 256, 0, stream>>>(
      wv, wT + (size_t)(NH * HD + NKV * HD) * HID, HID, NKV * HD);
  // 3. fused QKV projection
  gemm_mfma<<<dim3(NQKV / 128, SEQ / 128), 256, 0, stream>>>(
      xb, wT, bq, nullptr, qb, kb_, vbT, bk, bv, SEQ, NQKV, HID, 3);
  // 4. RoPE on q, k
  rope_kernel<<<dim3(SEQ, NH), 64, 0, stream>>>(qb, cosd, sind, NH);
  rope_kernel<<<dim3(SEQ, NKV), 64, 0, stream>>>(kb_, cosd, sind, NKV);
  // 5. split-K attention + reduce
  attn_split<<<dim3(NSLOT, NH), 256, 0, stream>>>(qb, kb_, vbT, Opart, Mpart, Lpart);
  attn_reduce<<<dim3(SEQ, NH), 128, 0, stream>>>(Opart, Mpart, Lpart, aob);
  // 6. output projection (reuse wT region for wo^T; partials dead after reduce)
  transpose_cast_kernel<<<dim3(HID / 64, HID / 64), 256, 0, stream>>>(wo, wT, HID, HID);
  gemm_mfma<<<dim3(HID / 128, SEQ / 128), 256, 0, stream>>>(
      aob, wT, nullptr, out, nullptr, nullptr, nullptr, nullptr, nullptr, SEQ, HID, HID, 0);
}

// Round 7
// 429.077 us; speedup vs baseline: 18.6981x; 1.0185x over previous
//
#include <hip/hip_runtime.h>
#include <math.h>

#define SEQ 2048
#define HID 3584
#define NH 28
#define NKV 4
#define HD 128
#define GQA (NH / NKV)
#define NQKV (NH * HD + 2 * NKV * HD)  // 4608
#define NSLOT 60                       // (qtile, chunk) slots per head, QBLK=64, CHUNK=12 tiles
#define KS2 0.12752997f                // (1/sqrt(128)) * log2(e)
#define DTHR 90.50967f                 // 8 / (1/sqrt(128)) : defer-max threshold (raw domain)

typedef __attribute__((ext_vector_type(8))) short short8;
typedef __attribute__((ext_vector_type(4))) float f32x4;
typedef unsigned int u32;
typedef unsigned short ushort_t;

__device__ inline ushort_t f2bf(float f) {
  u32 x = __float_as_uint(f);
  return (ushort_t)((x + 0x7FFFu + ((x >> 16) & 1u)) >> 16);
}
__device__ inline float bf2f(ushort_t h) {
  return __uint_as_float(((u32)h) << 16);
}
__device__ inline void gload16(const void* g, void* l) {
  __builtin_amdgcn_global_load_lds((const u32 __attribute__((address_space(1)))*)g,
                                   (u32 __attribute__((address_space(3)))*)l, 16, 0, 0);
}

// ---------------- cast x -> bf16 ----------------
__global__ __launch_bounds__(256) void cast_bf16_kernel(const float* __restrict__ in,
                                                        ushort_t* __restrict__ out, int n4) {
  int i = blockIdx.x * blockDim.x + threadIdx.x;
  if (i >= n4) return;
  float4 v = ((const float4*)in)[i];
  ushort4 o;
  o.x = f2bf(v.x); o.y = f2bf(v.y); o.z = f2bf(v.z); o.w = f2bf(v.w);
  *(ushort4*)&out[(size_t)i * 4] = o;
}

// ---------------- transpose-cast: in [K][N] f32 -> out [N][K] bf16 ----------------
__global__ __launch_bounds__(256) void transpose_cast_kernel(const float* __restrict__ in,
                                                             ushort_t* __restrict__ out,
                                                             int K, int N) {
  __shared__ ushort_t t[64][65];
  const int bk = blockIdx.y * 64, bn = blockIdx.x * 64;
  const int tid = threadIdx.x;
#pragma unroll
  for (int i = 0; i < 4; i++) {
    int idx = i * 256 + tid;
    int r = idx >> 4, c4 = idx & 15;
    float4 v = *(const float4*)&in[(size_t)(bk + r) * N + bn + c4 * 4];
    t[c4 * 4 + 0][r] = f2bf(v.x);
    t[c4 * 4 + 1][r] = f2bf(v.y);
    t[c4 * 4 + 2][r] = f2bf(v.z);
    t[c4 * 4 + 3][r] = f2bf(v.w);
  }
  __syncthreads();
#pragma unroll
  for (int i = 0; i < 4; i++) {
    int idx = i * 256 + tid;
    int r = idx >> 4, c4 = idx & 15;
    ushort4 o;
    o.x = t[r][c4 * 4 + 0]; o.y = t[r][c4 * 4 + 1];
    o.z = t[r][c4 * 4 + 2]; o.w = t[r][c4 * 4 + 3];
    *(ushort4*)&out[(size_t)(bn + r) * K + bk + c4 * 4] = o;
  }
}

// ---------------- bf16 MFMA GEMM ----------------
// C[M][N] = A[M][K] @ BT[N][K]^T (+bias).
// mode 0: f32 out (Cf). mode 1: bf16 out (Cb).
// mode 3: fused QKV routing: cols [0,3584)->Cb (q), [3584,4096)->Ck (k),
//         [4096,4608)->Cv transposed (vT).
__global__ __launch_bounds__(256) void gemm_mfma(
    const ushort_t* __restrict__ A, const ushort_t* __restrict__ BT,
    const float* __restrict__ bias, float* __restrict__ Cf, ushort_t* __restrict__ Cb,
    ushort_t* __restrict__ Ck, ushort_t* __restrict__ Cv,
    const float* __restrict__ bias_k, const float* __restrict__ bias_v,
    int M, int N, int K, int mode) {
  __shared__ __align__(16) ushort_t As[2][128 * 32];
  __shared__ __align__(16) ushort_t Bs[2][128 * 32];
  const int tid = threadIdx.x;
  const int w = tid >> 6, lane = tid & 63;
  const int g = lane >> 4, r16 = lane & 15;
  const int wr = w >> 1, wc = w & 1;
  const int bm = blockIdx.y * 128, bn = blockIdx.x * 128;

  f32x4 acc[4][4];
#pragma unroll
  for (int i = 0; i < 4; i++)
#pragma unroll
    for (int j = 0; j < 4; j++) acc[i][j] = (f32x4){0.f, 0.f, 0.f, 0.f};

  const int nk = K >> 5;
#pragma unroll
  for (int i = 0; i < 2; i++) {
    int gi = i * 256 + w * 64 + lane;
    int row = gi >> 2, gc = gi & 3;
    gload16(&A[(size_t)(bm + row) * K + gc * 8], &As[0][(i * 256 + w * 64) * 8]);
    gload16(&BT[(size_t)(bn + row) * K + gc * 8], &Bs[0][(i * 256 + w * 64) * 8]);
  }
  __syncthreads();

  int buf = 0;
  for (int kt = 0; kt < nk; kt++) {
    if (kt + 1 < nk) {
      const int k0 = (kt + 1) << 5;
#pragma unroll
      for (int i = 0; i < 2; i++) {
        int gi = i * 256 + w * 64 + lane;
        int row = gi >> 2, gc = gi & 3;
        gload16(&A[(size_t)(bm + row) * K + k0 + gc * 8], &As[buf ^ 1][(i * 256 + w * 64) * 8]);
        gload16(&BT[(size_t)(bn + row) * K + k0 + gc * 8], &Bs[buf ^ 1][(i * 256 + w * 64) * 8]);
      }
    }
    short8 af[4], bfr[4];
#pragma unroll
    for (int mi = 0; mi < 4; mi++)
      af[mi] = *(const short8*)&As[buf][((wr * 64 + mi * 16 + r16) * 4 + g) * 8];
#pragma unroll
    for (int ni = 0; ni < 4; ni++)
      bfr[ni] = *(const short8*)&Bs[buf][((wc * 64 + ni * 16 + r16) * 4 + g) * 8];
    __builtin_amdgcn_s_setprio(1);
#pragma unroll
    for (int mi = 0; mi < 4; mi++)
#pragma unroll
      for (int ni = 0; ni < 4; ni++)
        acc[mi][ni] = __builtin_amdgcn_mfma_f32_16x16x32_bf16(af[mi], bfr[ni], acc[mi][ni], 0, 0, 0);
    __builtin_amdgcn_s_setprio(0);
    __syncthreads();
    buf ^= 1;
  }

  if (mode == 3) {
#pragma unroll
    for (int mi = 0; mi < 4; mi++)
#pragma unroll
      for (int ni = 0; ni < 4; ni++)
#pragma unroll
        for (int r = 0; r < 4; r++) {
          int row = bm + wr * 64 + mi * 16 + 4 * g + r;
          int col = bn + wc * 64 + ni * 16 + r16;
          float v = acc[mi][ni][r];
          if (bn < NH * HD) {
            Cb[(size_t)row * (NH * HD) + col] = f2bf(v + bias[col]);
          } else if (bn < NH * HD + NKV * HD) {
            int c = col - NH * HD;
            Ck[(size_t)row * (NKV * HD) + c] = f2bf(v + bias_k[c]);
          } else {
            int c = col - (NH * HD + NKV * HD);
            Cv[(size_t)c * M + row] = f2bf(v + bias_v[c]);
          }
        }
    return;
  }
#pragma unroll
  for (int mi = 0; mi < 4; mi++)
#pragma unroll
    for (int ni = 0; ni < 4; ni++)
#pragma unroll
      for (int r = 0; r < 4; r++) {
        int row = bm + wr * 64 + mi * 16 + 4 * g + r;
        int col = bn + wc * 64 + ni * 16 + r16;
        float v = acc[mi][ni][r];
        if (bias) v += bias[col];
        if (mode == 0) Cf[(size_t)row * N + col] = v;
        else Cb[(size_t)row * N + col] = f2bf(v);
      }
}

// ---------------- RoPE in-place on bf16 [S][nheads][128] ----------------
__global__ void rope_kernel(ushort_t* __restrict__ buf, const float* __restrict__ cosd,
                            const float* __restrict__ sind, int nheads) {
  const int s = blockIdx.x, h = blockIdx.y, d = threadIdx.x;  // d: 0..63
  const float c = cosd[s * 64 + d], sn = sind[s * 64 + d];
  ushort_t* p = buf + ((size_t)s * nheads + h) * HD;
  float x1 = bf2f(p[d]), x2 = bf2f(p[d + 64]);
  p[d] = f2bf(x1 * c - x2 * sn);
  p[d + 64] = f2bf(x1 * sn + x2 * c);
}

// ---------------- split-K MFMA causal GQA flash attention ----------------
// Block = 64 q-rows x one chunk of <=12 K-tiles (64 keys each). 4 waves x 16 rows.
// K staged in LDS (dbuf prefetch, key&15 granule swizzle); V preloaded into
// registers per tile (batched issue, latency hidden under softmax).
// Lane-local lrow accumulation; shuffle-free common path (defer-max);
// cross-lane reduces only on rescale trigger and once at epilogue.
__global__ __launch_bounds__(256) void attn_split(
    const ushort_t* __restrict__ q, const ushort_t* __restrict__ k,
    const ushort_t* __restrict__ vT, ushort_t* __restrict__ Opart,
    float* __restrict__ Mpart, float* __restrict__ Lpart) {
  const int b = (NSLOT - 1) - blockIdx.x;  // longest chunks dispatch first
  int qt, c;
  if (b < 12) { qt = b; c = 0; }
  else if (b < 36) { qt = 12 + (b - 12) / 2; c = (b - 12) & 1; }
  else { qt = 24 + (b - 36) / 3; c = (b - 36) % 3; }
  const int h = blockIdx.y, kvh = h / GQA;
  const int q0 = qt * 64;
  const int tstart = c * 12;
  const int tend = min(tstart + 12, qt + 1);
  const int tid = threadIdx.x, w = tid >> 6, lane = tid & 63;
  const int g = lane >> 4, r16 = lane & 15;

  __shared__ __align__(16) ushort_t Ks[2][64 * 128];  // [key][d], granule ^= key&15
  __shared__ __align__(16) ushort_t Ps[4][16][72];    // per-wave P

  // Q fragment: rows q0 + w*16 + r16
  short8 qf[4];
  {
    const ushort_t* qp = q + (size_t)(q0 + w * 16 + r16) * (NH * HD) + h * HD;
#pragma unroll
    for (int f = 0; f < 4; f++) qf[f] = *(const short8*)(qp + f * 32 + g * 8);
  }
  float mrow[4], lrow[4];  // mrow row-uniform; lrow LANE-LOCAL partial
#pragma unroll
  for (int r = 0; r < 4; r++) { mrow[r] = -1e30f; lrow[r] = 0.f; }
  f32x4 oa[8];
#pragma unroll
  for (int d = 0; d < 8; d++) oa[d] = (f32x4){0.f, 0.f, 0.f, 0.f};

  const ushort_t* vbase = vT + (size_t)kvh * HD * SEQ;

#define STAGE(BUF, T)                                                                   \
  do {                                                                                  \
    const int kb_ = (T) * 64;                                                           \
    _Pragma("unroll") for (int i = 0; i < 4; i++) {                                     \
      int gi = i * 256 + w * 64 + lane;                                                 \
      int key = gi >> 4, gd = gi & 15;                                                  \
      int gsrc = gd ^ (key & 15);                                                       \
      gload16(&k[(size_t)(kb_ + key) * (NKV * HD) + kvh * HD + gsrc * 8],               \
              &Ks[BUF][(i * 256 + w * 64) * 8]);                                        \
    }                                                                                   \
  } while (0)

  STAGE(0, tstart);
  __syncthreads();  // vmcnt(0) drain: first tile resident

  for (int t = tstart; t < tend; t++) {
    const int cur = (t - tstart) & 1;
    const int kb = t * 64;
    if (t + 1 < tend) STAGE(cur ^ 1, t + 1);  // prefetch next K tile

    // ---- QK^T: S[16 rows][64 keys] (raw scores) ----
    f32x4 sfr[4];
    __builtin_amdgcn_s_setprio(1);
#pragma unroll
    for (int kb4 = 0; kb4 < 4; kb4++) {
      f32x4 acc = (f32x4){0.f, 0.f, 0.f, 0.f};
      const int key = kb4 * 16 + r16;
#pragma unroll
      for (int ks = 0; ks < 4; ks++) {
        short8 kf = *(const short8*)&Ks[cur][key * 128 + (((4 * ks + g) ^ (key & 15)) * 8)];
        acc = __builtin_amdgcn_mfma_f32_16x16x32_bf16(qf[ks], kf, acc, 0, 0, 0);
      }
      sfr[kb4] = acc;
    }
    __builtin_amdgcn_s_setprio(0);

    // ---- batched V preload into registers (latency hides under softmax) ----
    short8 vreg[16];
#pragma unroll
    for (int d = 0; d < 8; d++) {
      const ushort_t* vrow = vbase + (size_t)(d * 16 + r16) * SEQ + kb;
      vreg[2 * d]     = *(const short8*)(vrow + g * 8);
      vreg[2 * d + 1] = *(const short8*)(vrow + 32 + g * 8);
    }

    // causal mask: only final tile (t == qt) is partial
    if (t == qt) {
#pragma unroll
      for (int kb4 = 0; kb4 < 4; kb4++)
#pragma unroll
        for (int r = 0; r < 4; r++)
          if (kb4 * 16 + r16 > w * 16 + 4 * g + r) sfr[kb4][r] = -1e30f;
    }

    // ---- online softmax: shuffle-free common path ----
    float pm[4];
    bool need = false;
#pragma unroll
    for (int r = 0; r < 4; r++) {
      pm[r] = fmaxf(fmaxf(sfr[0][r], sfr[1][r]), fmaxf(sfr[2][r], sfr[3][r]));
      need |= (pm[r] > mrow[r] + DTHR);
    }
    if (__any(need)) {  // rare after first tile: full row-max reduce + rescale
#pragma unroll
      for (int r = 0; r < 4; r++) {
        float x = pm[r];
        x = fmaxf(x, __shfl_xor(x, 1));
        x = fmaxf(x, __shfl_xor(x, 2));
        x = fmaxf(x, __shfl_xor(x, 4));
        x = fmaxf(x, __shfl_xor(x, 8));
        float nm = fmaxf(mrow[r], x);
        float resc = exp2f((mrow[r] - nm) * KS2);
        mrow[r] = nm;
        lrow[r] *= resc;
#pragma unroll
        for (int d = 0; d < 8; d++) oa[d][r] *= resc;
      }
    }
#pragma unroll
    for (int kb4 = 0; kb4 < 4; kb4++)
#pragma unroll
      for (int r = 0; r < 4; r++) {
        float p = exp2f((sfr[kb4][r] - mrow[r]) * KS2);
        lrow[r] += p;  // lane-local partial sum
        Ps[w][4 * g + r][kb4 * 16 + r16] = f2bf(p);
      }

    // ---- PV: O[16][128] += P[16][64] @ V[64][128] (V already in regs) ----
    short8 pf[2];
    pf[0] = *(const short8*)&Ps[w][r16][g * 8];
    pf[1] = *(const short8*)&Ps[w][r16][32 + g * 8];
    __builtin_amdgcn_s_setprio(1);
#pragma unroll
    for (int d = 0; d < 8; d++) {
      oa[d] = __builtin_amdgcn_mfma_f32_16x16x32_bf16(pf[0], vreg[2 * d], oa[d], 0, 0, 0);
      oa[d] = __builtin_amdgcn_mfma_f32_16x16x32_bf16(pf[1], vreg[2 * d + 1], oa[d], 0, 0, 0);
    }
    __builtin_amdgcn_s_setprio(0);
    __syncthreads();  // K prefetch landed + all waves done with Ks[cur]
  }
#undef STAGE

  // epilogue: reduce lane-local lrow once, write unnormalized partials
#pragma unroll
  for (int r = 0; r < 4; r++) {
    float s = lrow[r];
    s += __shfl_xor(s, 1); s += __shfl_xor(s, 2);
    s += __shfl_xor(s, 4); s += __shfl_xor(s, 8);
    lrow[r] = s;
  }
  const size_t slot = (size_t)h * NSLOT + b;
#pragma unroll
  for (int d = 0; d < 8; d++)
#pragma unroll
    for (int r = 0; r < 4; r++) {
      int lr = w * 16 + 4 * g + r;
      Opart[(slot * 64 + lr) * 128 + d * 16 + r16] = f2bf(oa[d][r]);
    }
  if (r16 == 0) {
#pragma unroll
    for (int r = 0; r < 4; r++) {
      int lr = w * 16 + 4 * g + r;
      Mpart[slot * 64 + lr] = mrow[r];
      Lpart[slot * 64 + lr] = lrow[r];
    }
  }
}

// ---------------- combine split-K partials ----------------
__global__ __launch_bounds__(128) void attn_reduce(
    const ushort_t* __restrict__ Opart, const float* __restrict__ Mpart,
    const float* __restrict__ Lpart, ushort_t* __restrict__ out) {
  const int s = blockIdx.x, h = blockIdx.y, d = threadIdx.x;
  const int qt = s >> 6;
  int b0, C;
  if (qt < 12) { b0 = qt; C = 1; }
  else if (qt < 24) { b0 = 12 + 2 * (qt - 12); C = 2; }
  else { b0 = 36 + 3 * (qt - 24); C = 3; }
  const int lr = s & 63;
  const size_t base = ((size_t)h * NSLOT + b0) * 64 + lr;
  float M = -1e30f;
  for (int c = 0; c < C; c++) M = fmaxf(M, Mpart[base + c * 64]);
  float L = 0.f, O = 0.f;
  for (int c = 0; c < C; c++) {
    float wgt = exp2f((Mpart[base + c * 64] - M) * KS2);
    L += wgt * Lpart[base + c * 64];
    O += wgt * bf2f(Opart[(base + c * 64) * 128 + d]);
  }
  out[(size_t)s * (NH * HD) + h * HD + d] = f2bf(O / L);
}

extern "C" void kernel_launch(void* const* d_in, const int* in_sizes, int n_in,
                              void* d_out, int out_size, void* d_ws, size_t ws_size,
                              hipStream_t stream) {
  const float* x    = (const float*)d_in[0];
  const float* wq   = (const float*)d_in[1];
  const float* bq   = (const float*)d_in[2];
  const float* wk   = (const float*)d_in[3];
  const float* bk   = (const float*)d_in[4];
  const float* wv   = (const float*)d_in[5];
  const float* bv   = (const float*)d_in[6];
  const float* wo   = (const float*)d_in[7];
  const float* cosd = (const float*)d_in[8];
  const float* sind = (const float*)d_in[9];
  float* out = (float*)d_out;

  ushort_t* ws   = (ushort_t*)d_ws;
  ushort_t* wT   = ws;                              // [4608][3584] qkv^T; later partials; later wo^T
  ushort_t* xb   = wT + (size_t)NQKV * HID;         // [2048][3584] (later attn out)
  ushort_t* qb   = xb + (size_t)SEQ * HID;          // [2048][3584]
  ushort_t* kb_  = qb + (size_t)SEQ * HID;          // [2048][512]
  ushort_t* vbT  = kb_ + (size_t)SEQ * (NKV * HD);  // [512][2048]
  ushort_t* aob  = xb;                              // reuse after QKV GEMM

  // split-K partials overlay the (dead after QKV GEMM) wT region:
  // 28*60*64*128*2B = 27.5MB + 2*28*60*64*4B = 0.86MB <= 33MB
  ushort_t* Opart = wT;                                            // [28][60][64][128] bf16
  float* Mpart = (float*)(wT + (size_t)NH * NSLOT * 64 * 128);     // [28][60][64]
  float* Lpart = Mpart + (size_t)NH * NSLOT * 64;                  // [28][60][64]

  // 1. cast x -> bf16
  cast_bf16_kernel<<<(SEQ * HID / 4) / 256, 256, 0, stream>>>(x, xb, SEQ * HID / 4);
  // 2. transpose-cast weights into fused [4608][3584]
  transpose_cast_kernel<<<dim3(HID / 64, HID / 64), 256, 0, stream>>>(wq, wT, HID, HID);
  transpose_cast_kernel<<<dim3((NKV * HD) / 64, HID / 64), 256, 0, stream>>>(
      wk, wT + (size_t)(NH * HD) * HID, HID, NKV * HD);
  transpose_cast_kernel<<<dim3((NKV * HD) / 64, HID / 64), 256, 0, stream>>>(
      wv, wT + (size_t)(NH * HD + NKV * HD) * HID, HID, NKV * HD);
  // 3. fused QKV projection
  gemm_mfma<<<dim3(NQKV / 128, SEQ / 128), 256, 0, stream>>>(
      xb, wT, bq, nullptr, qb, kb_, vbT, bk, bv, SEQ, NQKV, HID, 3);
  // 4. RoPE on q, k
  rope_kernel<<<dim3(SEQ, NH), 64, 0, stream>>>(qb, cosd, sind, NH);
  rope_kernel<<<dim3(SEQ, NKV), 64, 0, stream>>>(kb_, cosd, sind, NKV);
  // 5. split-K attention + reduce
  attn_split<<<dim3(NSLOT, NH), 256, 0, stream>>>(qb, kb_, vbT, Opart, Mpart, Lpart);
  attn_reduce<<<dim3(SEQ, NH), 128, 0, stream>>>(Opart, Mpart, Lpart, aob);
  // 6. output projection (reuse wT region for wo^T; partials dead after reduce)
  transpose_cast_kernel<<<dim3(HID / 64, HID / 64), 256, 0, stream>>>(wo, wT, HID, HID);
  gemm_mfma<<<dim3(HID / 128, SEQ / 128), 256, 0, stream>>>(
      aob, wT, nullptr, out, nullptr, nullptr, nullptr, nullptr, nullptr, SEQ, HID, HID, 0);
}